// Round 1
// baseline (3201.786 us; speedup 1.0000x reference)
//
#include <hip/hip_runtime.h>

#define NN 30000
#define EE 300000
#define HD 128
#define D9 144
#define DI 512

__device__ __forceinline__ float sigmoidf_(float x) { return 1.0f / (1.0f + __expf(-x)); }
__device__ __forceinline__ float siluf_(float x) { return x / (1.0f + __expf(-x)); }

// ---------------- Kernel A: tensor_init ----------------
// One wave per node (4 nodes / 256-thread block). Lane l owns output features
// {l, 64+l, 128+l(<16)}. Wave-local shfl reduction for LayerNorm.
__global__ __launch_bounds__(256) void tensor_init_k(
    const float* __restrict__ h,
    const float* __restrict__ W1, const float* __restrict__ b1,
    const float* __restrict__ g1, const float* __restrict__ be1,
    const float* __restrict__ W2, const float* __restrict__ b2,
    const float* __restrict__ g2, const float* __restrict__ be2,
    float* __restrict__ tout)
{
    __shared__ float h_s[4][128];
    __shared__ float t_s[4][160];
    const int w = threadIdx.x >> 6;
    const int l = threadIdx.x & 63;
    const int n = blockIdx.x * 4 + w;

    h_s[w][l]      = h[n * HD + l];
    h_s[w][l + 64] = h[n * HD + l + 64];
    __syncthreads();

    const int j0 = l, j1 = 64 + l, j2 = 128 + (l & 15);

    // ---- layer 1: dot over 128 ----
    float a0 = 0.f, a1 = 0.f, a2 = 0.f;
    {
        const float4* r0 = (const float4*)(W1 + j0 * HD);
        const float4* r1 = (const float4*)(W1 + j1 * HD);
        const float4* r2 = (const float4*)(W1 + j2 * HD);
        const float4* hv = (const float4*)(&h_s[w][0]);
        #pragma unroll 8
        for (int kq = 0; kq < HD / 4; ++kq) {
            float4 hq = hv[kq];
            float4 x0 = r0[kq]; a0 += x0.x*hq.x + x0.y*hq.y + x0.z*hq.z + x0.w*hq.w;
            float4 x1 = r1[kq]; a1 += x1.x*hq.x + x1.y*hq.y + x1.z*hq.z + x1.w*hq.w;
            float4 x2 = r2[kq]; a2 += x2.x*hq.x + x2.y*hq.y + x2.z*hq.z + x2.w*hq.w;
        }
    }
    a0 += b1[j0]; a1 += b1[j1]; a2 += b1[j2];
    {
        float m2 = (l < 16) ? a2 : 0.f;
        float s = a0 + a1 + m2;
        float q = a0*a0 + a1*a1 + m2*m2;
        #pragma unroll
        for (int off = 32; off >= 1; off >>= 1) { s += __shfl_xor(s, off); q += __shfl_xor(q, off); }
        float mu = s * (1.0f / 144.0f);
        float rs = rsqrtf(q * (1.0f / 144.0f) - mu * mu + 1e-5f);
        float v0 = (a0 - mu) * rs * g1[j0] + be1[j0];
        float v1 = (a1 - mu) * rs * g1[j1] + be1[j1];
        float v2 = (a2 - mu) * rs * g1[j2] + be1[j2];
        t_s[w][j0] = siluf_(v0);
        t_s[w][j1] = siluf_(v1);
        if (l < 16) t_s[w][j2] = siluf_(v2);
    }
    __syncthreads();

    // ---- layer 2: dot over 144 ----
    a0 = a1 = a2 = 0.f;
    {
        const float4* r0 = (const float4*)(W2 + j0 * D9);
        const float4* r1 = (const float4*)(W2 + j1 * D9);
        const float4* r2 = (const float4*)(W2 + j2 * D9);
        const float4* tv = (const float4*)(&t_s[w][0]);
        #pragma unroll 6
        for (int kq = 0; kq < D9 / 4; ++kq) {
            float4 hq = tv[kq];
            float4 x0 = r0[kq]; a0 += x0.x*hq.x + x0.y*hq.y + x0.z*hq.z + x0.w*hq.w;
            float4 x1 = r1[kq]; a1 += x1.x*hq.x + x1.y*hq.y + x1.z*hq.z + x1.w*hq.w;
            float4 x2 = r2[kq]; a2 += x2.x*hq.x + x2.y*hq.y + x2.z*hq.z + x2.w*hq.w;
        }
    }
    a0 += b2[j0]; a1 += b2[j1]; a2 += b2[j2];
    {
        float m2 = (l < 16) ? a2 : 0.f;
        float s = a0 + a1 + m2;
        float q = a0*a0 + a1*a1 + m2*m2;
        #pragma unroll
        for (int off = 32; off >= 1; off >>= 1) { s += __shfl_xor(s, off); q += __shfl_xor(q, off); }
        float mu = s * (1.0f / 144.0f);
        float rs = rsqrtf(q * (1.0f / 144.0f) - mu * mu + 1e-5f);
        float v0 = (a0 - mu) * rs * g2[j0] + be2[j0];
        float v1 = (a1 - mu) * rs * g2[j1] + be2[j1];
        float v2 = (a2 - mu) * rs * g2[j2] + be2[j2];
        tout[n * D9 + j0] = siluf_(v0);
        tout[n * D9 + j1] = siluf_(v1);
        if (l < 16) tout[n * D9 + j2] = siluf_(v2);
    }
}

// ---------------- Kernel B: edges ----------------
// 16 edges per 256-thread block.
// Phase 1: gather s = [h[col] | h[row]] into LDS (float4, coalesced).
// Phase 2: z[e][j] GEMM: thread t owns columns {t, t+256} x 16 edges.
//          LDS s reads are wave-uniform (broadcast). Wi streamed from L2.
// Phase 2b: per-edge LN (block reduce) + sigmoid -> wbuf.
// Phase 3: R_rel, rotate tj (R@T@R per the einsum!), stage stacked tensor,
//          contract with weights, symmetrize, atomic scatter to out[col].
__global__ __launch_bounds__(256) void edge_k(
    const float* __restrict__ h,
    const float* __restrict__ frames,
    const int* __restrict__ ei,
    const float* __restrict__ tens,
    const float* __restrict__ Wi, const float* __restrict__ bi,
    const float* __restrict__ gi, const float* __restrict__ bei,
    float* __restrict__ out)
{
    __shared__ float wbuf[16 * 520];   // weights w[e][512], e-stride 520 (bank spread)
    __shared__ float sbuf[16 * 392];   // s[e][256] first; reused as stacked[e][32][12]
    __shared__ int   col_s[16], row_s[16];
    __shared__ float rrel_s[16][9];
    __shared__ float red_s[4][16][2];
    __shared__ float mu_s[16], rs_s[16];

    const int t = threadIdx.x;
    const int e0 = blockIdx.x * 16;

    if (t < 16) {
        int v = ei[e0 + t];
        row_s[t] = v < 0 ? 0 : (v >= NN ? NN - 1 : v);
    } else if (t < 32) {
        int v = ei[EE + e0 + (t - 16)];
        col_s[t - 16] = v < 0 ? 0 : (v >= NN ? NN - 1 : v);
    }
    __syncthreads();

    // ---- phase 1: gather ----
    {
        const int eo = t >> 6;          // 0..3
        const int q4 = (t & 63) * 4;    // 0..252
        #pragma unroll
        for (int g = 0; g < 4; ++g) {
            int e = g * 4 + eo;
            int src = (q4 < 128) ? (col_s[e] * HD + q4) : (row_s[e] * HD + (q4 - 128));
            float4 val = *(const float4*)(h + src);
            *(float4*)(&sbuf[e * 256 + q4]) = val;
        }
    }
    __syncthreads();

    // ---- phase 2: GEMM z = s @ Wi^T ----
    float z0[16], z1[16];
    #pragma unroll
    for (int e = 0; e < 16; ++e) { z0[e] = 0.f; z1[e] = 0.f; }
    {
        const float4* wr0 = (const float4*)(Wi + (size_t)t * 256);
        const float4* wr1 = (const float4*)(Wi + (size_t)(t + 256) * 256);
        #pragma unroll 2
        for (int kq = 0; kq < 64; ++kq) {
            float4 a = wr0[kq];
            float4 b = wr1[kq];
            #pragma unroll
            for (int e = 0; e < 16; ++e) {
                float4 sv = *(const float4*)(&sbuf[e * 256 + kq * 4]);
                z0[e] += a.x*sv.x + a.y*sv.y + a.z*sv.z + a.w*sv.w;
                z1[e] += b.x*sv.x + b.y*sv.y + b.z*sv.z + b.w*sv.w;
            }
        }
    }
    {
        const float bi0 = bi[t], bi1 = bi[t + 256];
        #pragma unroll
        for (int e = 0; e < 16; ++e) { z0[e] += bi0; z1[e] += bi1; }
    }

    // ---- phase 2b: LayerNorm stats + sigmoid ----
    {
        const int wv = t >> 6, ln = t & 63;
        #pragma unroll
        for (int e = 0; e < 16; ++e) {
            float s = z0[e] + z1[e];
            float q = z0[e]*z0[e] + z1[e]*z1[e];
            #pragma unroll
            for (int off = 32; off >= 1; off >>= 1) { s += __shfl_xor(s, off); q += __shfl_xor(q, off); }
            if (ln == 0) { red_s[wv][e][0] = s; red_s[wv][e][1] = q; }
        }
    }
    __syncthreads();
    if (t < 16) {
        float s = red_s[0][t][0] + red_s[1][t][0] + red_s[2][t][0] + red_s[3][t][0];
        float q = red_s[0][t][1] + red_s[1][t][1] + red_s[2][t][1] + red_s[3][t][1];
        float mu = s * (1.0f / 512.0f);
        mu_s[t] = mu;
        rs_s[t] = rsqrtf(q * (1.0f / 512.0f) - mu * mu + 1e-5f);
    }
    __syncthreads();
    {
        const float gi0 = gi[t], gi1 = gi[t + 256];
        const float beA = bei[t], beB = bei[t + 256];
        #pragma unroll
        for (int e = 0; e < 16; ++e) {
            float mu = mu_s[e], rs = rs_s[e];
            wbuf[e * 520 + t]       = sigmoidf_((z0[e] - mu) * rs * gi0 + beA);
            wbuf[e * 520 + t + 256] = sigmoidf_((z1[e] - mu) * rs * gi1 + beB);
        }
    }
    __syncthreads();

    // ---- phase 3a: R_rel = Ri^T @ Rj ----
    if (t < 144) {
        int e = t / 9, cc = t - e * 9;
        int i = cc / 3, j = cc - i * 3;
        const float* Ri = frames + col_s[e] * 9;
        const float* Rj = frames + row_s[e] * 9;
        rrel_s[e][cc] = Ri[i] * Rj[j] + Ri[3 + i] * Rj[3 + j] + Ri[6 + i] * Rj[6 + j];
    }
    __syncthreads();

    // ---- phase 3b: rotate tj, stage stacked tensor ----
    const int e = t >> 4, c = t & 15;
    {
        float R[9];
        #pragma unroll
        for (int m = 0; m < 9; ++m) R[m] = rrel_s[e][m];
        float T[9], A[9], B[9];
        const float* tjp = tens + (size_t)row_s[e] * D9 + c * 9;
        #pragma unroll
        for (int m = 0; m < 9; ++m) T[m] = tjp[m];
        // A = R_rel @ T ; B = A @ R_rel   (einsum 'eik,eckl,elj->ecij')
        #pragma unroll
        for (int i = 0; i < 3; ++i)
            #pragma unroll
            for (int j = 0; j < 3; ++j)
                A[i*3+j] = R[i*3+0]*T[0*3+j] + R[i*3+1]*T[1*3+j] + R[i*3+2]*T[2*3+j];
        #pragma unroll
        for (int i = 0; i < 3; ++i)
            #pragma unroll
            for (int j = 0; j < 3; ++j)
                B[i*3+j] = A[i*3+0]*R[0*3+j] + A[i*3+1]*R[1*3+j] + A[i*3+2]*R[2*3+j];
        const float* tip = tens + (size_t)col_s[e] * D9 + c * 9;
        float* st = sbuf;
        #pragma unroll
        for (int m = 0; m < 9; ++m) st[e * 392 + c * 12 + m] = tip[m];
        #pragma unroll
        for (int m = 0; m < 9; ++m) st[e * 392 + (16 + c) * 12 + m] = B[m];
    }
    __syncthreads();

    // ---- phase 3c: t_new[c] = sum_k stacked[k] * w[k*16+c]; symmetrize; scatter ----
    {
        float o[9];
        #pragma unroll
        for (int m = 0; m < 9; ++m) o[m] = 0.f;
        const float* wp = wbuf + e * 520 + c;
        const float* st = sbuf + e * 392;
        for (int k = 0; k < 32; ++k) {
            float wk = wp[k * 16];
            const float* sp = st + k * 12;
            #pragma unroll
            for (int m = 0; m < 9; ++m) o[m] += sp[m] * wk;
        }
        float s01 = 0.5f * (o[1] + o[3]);
        float s02 = 0.5f * (o[2] + o[6]);
        float s12 = 0.5f * (o[5] + o[7]);
        float* op = out + (size_t)col_s[e] * D9 + c * 9;
        atomicAdd(op + 0, o[0]);
        atomicAdd(op + 1, s01);
        atomicAdd(op + 2, s02);
        atomicAdd(op + 3, s01);
        atomicAdd(op + 4, o[4]);
        atomicAdd(op + 5, s12);
        atomicAdd(op + 6, s02);
        atomicAdd(op + 7, s12);
        atomicAdd(op + 8, o[8]);
    }
}

extern "C" void kernel_launch(void* const* d_in, const int* in_sizes, int n_in,
                              void* d_out, int out_size, void* d_ws, size_t ws_size,
                              hipStream_t stream) {
    const float* h      = (const float*)d_in[1];
    const float* frames = (const float*)d_in[2];
    const int*   ei     = (const int*)d_in[3];
    const float* W1  = (const float*)d_in[5];
    const float* b1  = (const float*)d_in[6];
    const float* g1  = (const float*)d_in[7];
    const float* be1 = (const float*)d_in[8];
    const float* W2  = (const float*)d_in[9];
    const float* b2  = (const float*)d_in[10];
    const float* g2  = (const float*)d_in[11];
    const float* be2 = (const float*)d_in[12];
    const float* Wi  = (const float*)d_in[13];
    const float* bi  = (const float*)d_in[14];
    const float* gi  = (const float*)d_in[15];
    const float* bei = (const float*)d_in[16];

    float* out     = (float*)d_out;
    float* tensors = (float*)d_ws;   // [N,144] = 17.28 MB scratch

    hipMemsetAsync(d_out, 0, (size_t)out_size * sizeof(float), stream);

    tensor_init_k<<<NN / 4, 256, 0, stream>>>(h, W1, b1, g1, be1, W2, b2, g2, be2, tensors);
    edge_k<<<EE / 16, 256, 0, stream>>>(h, frames, ei, tensors, Wi, bi, gi, bei, out);
}

// Round 4
// 2401.222 us; speedup vs baseline: 1.3334x; 1.3334x over previous
//
#include <hip/hip_runtime.h>

#define NN 30000
#define EE 300000
#define HD 128
#define D9 144

typedef unsigned int uint32;
typedef unsigned short u16;
typedef __attribute__((ext_vector_type(8))) short short8;
typedef __attribute__((ext_vector_type(4))) float f32x4;

__device__ __forceinline__ float sigmoidf_(float x){ return 1.0f/(1.0f+__expf(-x)); }
__device__ __forceinline__ float siluf_(float x){ return x/(1.0f+__expf(-x)); }
__device__ __forceinline__ u16 f2bf(float f){
  uint32 u = __float_as_uint(f);
  return (u16)((u + 0x7fffu + ((u>>16)&1u)) >> 16);   // RNE
}
__device__ __forceinline__ float bf2f(u16 b){ return __uint_as_float(((uint32)b)<<16); }

// ---------------- f32 -> (bf16 hi, bf16 lo) splitter ----------------
__global__ __launch_bounds__(256) void cvt_split_k(const float* __restrict__ src,
                                                   u16* __restrict__ hi, u16* __restrict__ lo, int n){
  int i = blockIdx.x*256 + threadIdx.x;
  if (i < n){
    float x = src[i];
    u16 hh = f2bf(x);
    hi[i] = hh;
    lo[i] = f2bf(x - bf2f(hh));
  }
}

// ---------------- Kernel A: tensor_init (all-f32, round-1 verified) ----------------
__global__ __launch_bounds__(256) void tensor_init_k(
    const float* __restrict__ h,
    const float* __restrict__ W1, const float* __restrict__ b1,
    const float* __restrict__ g1, const float* __restrict__ be1,
    const float* __restrict__ W2, const float* __restrict__ b2,
    const float* __restrict__ g2, const float* __restrict__ be2,
    float* __restrict__ tout)
{
    __shared__ float h_s[4][128];
    __shared__ float t_s[4][160];
    const int w = threadIdx.x >> 6;
    const int l = threadIdx.x & 63;
    const int n = blockIdx.x * 4 + w;

    h_s[w][l]      = h[n * HD + l];
    h_s[w][l + 64] = h[n * HD + l + 64];
    __syncthreads();

    const int j0 = l, j1 = 64 + l, j2 = 128 + (l & 15);

    float a0 = 0.f, a1 = 0.f, a2 = 0.f;
    {
        const float4* r0 = (const float4*)(W1 + j0 * HD);
        const float4* r1 = (const float4*)(W1 + j1 * HD);
        const float4* r2 = (const float4*)(W1 + j2 * HD);
        const float4* hv = (const float4*)(&h_s[w][0]);
        #pragma unroll 8
        for (int kq = 0; kq < HD / 4; ++kq) {
            float4 hq = hv[kq];
            float4 x0 = r0[kq]; a0 += x0.x*hq.x + x0.y*hq.y + x0.z*hq.z + x0.w*hq.w;
            float4 x1 = r1[kq]; a1 += x1.x*hq.x + x1.y*hq.y + x1.z*hq.z + x1.w*hq.w;
            float4 x2 = r2[kq]; a2 += x2.x*hq.x + x2.y*hq.y + x2.z*hq.z + x2.w*hq.w;
        }
    }
    a0 += b1[j0]; a1 += b1[j1]; a2 += b1[j2];
    {
        float m2 = (l < 16) ? a2 : 0.f;
        float s = a0 + a1 + m2;
        float q = a0*a0 + a1*a1 + m2*m2;
        #pragma unroll
        for (int off = 32; off >= 1; off >>= 1) { s += __shfl_xor(s, off); q += __shfl_xor(q, off); }
        float mu = s * (1.0f / 144.0f);
        float rs = rsqrtf(q * (1.0f / 144.0f) - mu * mu + 1e-5f);
        t_s[w][j0] = siluf_((a0 - mu) * rs * g1[j0] + be1[j0]);
        t_s[w][j1] = siluf_((a1 - mu) * rs * g1[j1] + be1[j1]);
        if (l < 16) t_s[w][j2] = siluf_((a2 - mu) * rs * g1[j2] + be1[j2]);
    }
    __syncthreads();

    a0 = a1 = a2 = 0.f;
    {
        const float4* r0 = (const float4*)(W2 + j0 * D9);
        const float4* r1 = (const float4*)(W2 + j1 * D9);
        const float4* r2 = (const float4*)(W2 + j2 * D9);
        const float4* tv = (const float4*)(&t_s[w][0]);
        #pragma unroll 6
        for (int kq = 0; kq < D9 / 4; ++kq) {
            float4 hq = tv[kq];
            float4 x0 = r0[kq]; a0 += x0.x*hq.x + x0.y*hq.y + x0.z*hq.z + x0.w*hq.w;
            float4 x1 = r1[kq]; a1 += x1.x*hq.x + x1.y*hq.y + x1.z*hq.z + x1.w*hq.w;
            float4 x2 = r2[kq]; a2 += x2.x*hq.x + x2.y*hq.y + x2.z*hq.z + x2.w*hq.w;
        }
    }
    a0 += b2[j0]; a1 += b2[j1]; a2 += b2[j2];
    {
        float m2 = (l < 16) ? a2 : 0.f;
        float s = a0 + a1 + m2;
        float q = a0*a0 + a1*a1 + m2*m2;
        #pragma unroll
        for (int off = 32; off >= 1; off >>= 1) { s += __shfl_xor(s, off); q += __shfl_xor(q, off); }
        float mu = s * (1.0f / 144.0f);
        float rs = rsqrtf(q * (1.0f / 144.0f) - mu * mu + 1e-5f);
        tout[n * D9 + j0] = siluf_((a0 - mu) * rs * g2[j0] + be2[j0]);
        tout[n * D9 + j1] = siluf_((a1 - mu) * rs * g2[j1] + be2[j1]);
        if (l < 16) tout[n * D9 + j2] = siluf_((a2 - mu) * rs * g2[j2] + be2[j2]);
    }
}

// ---------------- Kernel B: edges ----------------
// 16 edges/block, 256 threads (4 waves). LDS 57.3 KB -> 2 blocks/CU.
// GEMM via bf16x3-split MFMA (fp32-equivalent): z = aH*bH + aL*bH + aH*bL.
// A fragments (hi/lo) built in-register from f32 h. Wi pre-split hi/lo bf16.
// w and tensors stay f32 end-to-end after the GEMM.
#define WLO 131072   // element offset of W_lo within Wspl
__global__ __launch_bounds__(256) void edge_k(
    const float* __restrict__ h,
    const float* __restrict__ frames,
    const int* __restrict__ ei,
    const float* __restrict__ tens,
    const u16* __restrict__ Wspl,
    const float* __restrict__ bi, const float* __restrict__ gi, const float* __restrict__ bei,
    float* __restrict__ out)
{
  __shared__ __align__(16) float wbuf[16 * 516];  // w[e][512] f32, edge stride 516
  __shared__ __align__(16) float st[16 * 388];    // stacked[e][32][12] f32, edge stride 388
  __shared__ int ei_s[32];                        // [0..15]=row, [16..31]=col
  __shared__ float pool[160];                     // LN red/mu/rs; reused as rrel[0..143]

  const int t  = threadIdx.x;
  const int w  = t >> 6;
  const int l  = t & 63;
  const int lr = l & 15;
  const int lg = l >> 4;
  const int eb = blockIdx.x * 16;

  if (t < 16)      { int v = ei[eb + t];          ei_s[t] = v < 0 ? 0 : (v >= NN ? NN - 1 : v); }  // row
  else if (t < 32) { int v = ei[EE + eb + (t-16)]; ei_s[t] = v < 0 ? 0 : (v >= NN ? NN - 1 : v); } // col
  __syncthreads();

  // ================= GEMM: z[16 x 512] = [hi|hj] @ Wi^T (bf16x3 MFMA) =================
  const float* qAc = h + (size_t)ei_s[16 + lr] * HD + lg*8;  // hi = h[col]  (k < 128)
  const float* qAr = h + (size_t)ei_s[lr]      * HD + lg*8;  // hj = h[row]  (k >= 128)
  const u16* pB[8];
  #pragma unroll
  for (int nt = 0; nt < 8; ++nt)
    pB[nt] = Wspl + (size_t)(w*128 + nt*16 + lr) * 256 + lg*8;

  f32x4 acc[8];
  #pragma unroll
  for (int nt = 0; nt < 8; ++nt) acc[nt] = (f32x4){0.f, 0.f, 0.f, 0.f};

  #pragma unroll
  for (int ks = 0; ks < 8; ++ks){
    const float* qa = (ks < 4) ? (qAc + ks*32) : (qAr + (ks-4)*32);
    float4 x0 = *(const float4*)qa;
    float4 x1 = *(const float4*)(qa + 4);
    float xs[8] = {x0.x, x0.y, x0.z, x0.w, x1.x, x1.y, x1.z, x1.w};
    short8 aH, aL;
    #pragma unroll
    for (int j = 0; j < 8; ++j){
      u16 hh = f2bf(xs[j]);
      aH[j] = (short)hh;
      aL[j] = (short)f2bf(xs[j] - bf2f(hh));
    }
    #pragma unroll
    for (int nt = 0; nt < 8; ++nt){
      short8 bH = *(const short8*)(pB[nt] + ks*32);
      short8 bL = *(const short8*)(pB[nt] + WLO + ks*32);
      acc[nt] = __builtin_amdgcn_mfma_f32_16x16x32_bf16(aH, bH, acc[nt], 0, 0, 0);
      acc[nt] = __builtin_amdgcn_mfma_f32_16x16x32_bf16(aL, bH, acc[nt], 0, 0, 0);
      acc[nt] = __builtin_amdgcn_mfma_f32_16x16x32_bf16(aH, bL, acc[nt], 0, 0, 0);
    }
  }

  // ================= LayerNorm over 512 per edge + sigmoid (f32) =================
  float biv[8], giv[8], bev[8];
  #pragma unroll
  for (int nt = 0; nt < 8; ++nt){
    int n = w*128 + nt*16 + lr;
    biv[nt] = bi[n]; giv[nt] = gi[n]; bev[nt] = bei[n];
  }
  float zs[4], zq[4];
  #pragma unroll
  for (int r = 0; r < 4; ++r){
    float s = 0.f, q = 0.f;
    #pragma unroll
    for (int nt = 0; nt < 8; ++nt){
      float z = acc[nt][r] + biv[nt];
      s += z; q += z*z;
    }
    zs[r] = s; zq[r] = q;
  }
  #pragma unroll
  for (int off = 1; off < 16; off <<= 1){
    #pragma unroll
    for (int r = 0; r < 4; ++r){
      zs[r] += __shfl_xor(zs[r], off);
      zq[r] += __shfl_xor(zq[r], off);
    }
  }
  if (lr == 0){
    #pragma unroll
    for (int r = 0; r < 4; ++r){
      int e = lg*4 + r;
      pool[w*32 + e*2 + 0] = zs[r];
      pool[w*32 + e*2 + 1] = zq[r];
    }
  }
  __syncthreads();
  if (t < 16){
    float s = pool[t*2]     + pool[32 + t*2]     + pool[64 + t*2]     + pool[96 + t*2];
    float q = pool[t*2 + 1] + pool[32 + t*2 + 1] + pool[64 + t*2 + 1] + pool[96 + t*2 + 1];
    float mu = s * (1.0f / 512.0f);
    pool[128 + t] = mu;
    pool[144 + t] = rsqrtf(q * (1.0f / 512.0f) - mu*mu + 1e-5f);
  }
  __syncthreads();
  #pragma unroll
  for (int r = 0; r < 4; ++r){
    int e = lg*4 + r;
    float mu = pool[128 + e], rs = pool[144 + e];
    #pragma unroll
    for (int nt = 0; nt < 8; ++nt){
      int n = w*128 + nt*16 + lr;
      float z = acc[nt][r] + biv[nt];
      wbuf[e*516 + n] = sigmoidf_((z - mu) * rs * giv[nt] + bev[nt]);
    }
  }
  __syncthreads();   // wbuf ready; pool (red/mu/rs) dead

  // ================= R_rel = Ri^T @ Rj  (pool[0..143]) =================
  if (t < 144){
    int e = t / 9, cc = t - e*9;
    int i = cc / 3, j = cc - i*3;
    const float* Ri = frames + (size_t)ei_s[16 + e] * 9;  // col
    const float* Rj = frames + (size_t)ei_s[e] * 9;       // row
    pool[t] = Ri[i]*Rj[j] + Ri[3+i]*Rj[3+j] + Ri[6+i]*Rj[6+j];
  }
  __syncthreads();

  // ================= rotate tj, stage stacked tensors (f32) =================
  const int e3 = t >> 4;
  const int c  = t & 15;
  {
    float R[9];
    #pragma unroll
    for (int m = 0; m < 9; ++m) R[m] = pool[e3*9 + m];

    const float* tjp = tens + (size_t)ei_s[e3]      * D9 + c*9;  // tj = tensors[row]
    const float* tip = tens + (size_t)ei_s[16 + e3] * D9 + c*9;  // ti = tensors[col]
    float T[9];
    #pragma unroll
    for (int m = 0; m < 9; ++m) T[m] = tjp[m];

    // B = R @ T @ R   (einsum 'eik,eckl,elj->ecij')
    float A[9], B[9];
    #pragma unroll
    for (int i = 0; i < 3; ++i)
      #pragma unroll
      for (int j = 0; j < 3; ++j)
        A[i*3+j] = R[i*3+0]*T[0+j] + R[i*3+1]*T[3+j] + R[i*3+2]*T[6+j];
    #pragma unroll
    for (int i = 0; i < 3; ++i)
      #pragma unroll
      for (int j = 0; j < 3; ++j)
        B[i*3+j] = A[i*3+0]*R[0+j] + A[i*3+1]*R[3+j] + A[i*3+2]*R[6+j];

    float* se = st + e3*388;
    #pragma unroll
    for (int m = 0; m < 9; ++m) se[c*12 + m] = tip[m];          // k = c       : ti
    #pragma unroll
    for (int m = 0; m < 9; ++m) se[(16 + c)*12 + m] = B[m];     // k = 16 + c  : R tj R
  }
  __syncthreads();

  // ================= contraction + symmetrize + scatter =================
  {
    float o[9];
    #pragma unroll
    for (int m = 0; m < 9; ++m) o[m] = 0.f;
    const float* se = st + e3*388;
    const float* wp = wbuf + e3*516 + c;
    #pragma unroll 4
    for (int k = 0; k < 32; ++k){
      float wk = wp[k*16];
      const float* sp = se + k*12;
      #pragma unroll
      for (int m = 0; m < 9; ++m) o[m] += sp[m] * wk;
    }
    float s01 = 0.5f*(o[1]+o[3]), s02 = 0.5f*(o[2]+o[6]), s12 = 0.5f*(o[5]+o[7]);
    float* op = out + (size_t)ei_s[16 + e3] * D9 + c*9;
    atomicAdd(op+0, o[0]); atomicAdd(op+1, s01);  atomicAdd(op+2, s02);
    atomicAdd(op+3, s01);  atomicAdd(op+4, o[4]); atomicAdd(op+5, s12);
    atomicAdd(op+6, s02);  atomicAdd(op+7, s12);  atomicAdd(op+8, o[8]);
  }
}

extern "C" void kernel_launch(void* const* d_in, const int* in_sizes, int n_in,
                              void* d_out, int out_size, void* d_ws, size_t ws_size,
                              hipStream_t stream) {
    const float* h      = (const float*)d_in[1];
    const float* frames = (const float*)d_in[2];
    const int*   ei     = (const int*)d_in[3];
    const float* W1  = (const float*)d_in[5];
    const float* b1  = (const float*)d_in[6];
    const float* g1  = (const float*)d_in[7];
    const float* be1 = (const float*)d_in[8];
    const float* W2  = (const float*)d_in[9];
    const float* b2  = (const float*)d_in[10];
    const float* g2  = (const float*)d_in[11];
    const float* be2 = (const float*)d_in[12];
    const float* Wi  = (const float*)d_in[13];
    const float* bi  = (const float*)d_in[14];
    const float* gi  = (const float*)d_in[15];
    const float* bei = (const float*)d_in[16];

    float* out = (float*)d_out;

    // ws layout (17.8 MB, within the 25.2 MB proven budget):
    u16*   Wspl = (u16*)d_ws;                    // [2][512,256] bf16 hi|lo : 524,288 B
    float* tens = (float*)((char*)d_ws + 524288); // [N,144] f32 : 17,280,000 B (16B-aligned)

    hipMemsetAsync(d_out, 0, (size_t)out_size * sizeof(float), stream);

    cvt_split_k<<<512, 256, 0, stream>>>(Wi, Wspl, Wspl + WLO, 512*256);
    tensor_init_k<<<NN/4, 256, 0, stream>>>(h, W1, b1, g1, be1, W2, b2, g2, be2, tens);
    edge_k<<<EE/16, 256, 0, stream>>>(h, frames, ei, tens, Wspl, bi, gi, bei, out);
}

// Round 5
// 2211.331 us; speedup vs baseline: 1.4479x; 1.0859x over previous
//
#include <hip/hip_runtime.h>

#define NN 30000
#define EE 300000
#define HD 128
#define D9 144

typedef unsigned int uint32;
typedef unsigned short u16;
typedef __attribute__((ext_vector_type(8))) short short8;
typedef __attribute__((ext_vector_type(4))) float f32x4;

__device__ __forceinline__ float sigmoidf_(float x){ return 1.0f/(1.0f+__expf(-x)); }
__device__ __forceinline__ float siluf_(float x){ return x/(1.0f+__expf(-x)); }
__device__ __forceinline__ u16 f2bf(float f){
  uint32 u = __float_as_uint(f);
  return (u16)((u + 0x7fffu + ((u>>16)&1u)) >> 16);   // RNE
}
__device__ __forceinline__ float bf2f(u16 b){ return __uint_as_float(((uint32)b)<<16); }

// ---------------- f32 -> (bf16 hi, bf16 lo) splitter ----------------
__global__ __launch_bounds__(256) void cvt_split_k(const float* __restrict__ src,
                                                   u16* __restrict__ hi, u16* __restrict__ lo, int n){
  int i = blockIdx.x*256 + threadIdx.x;
  if (i < n){
    float x = src[i];
    u16 hh = f2bf(x);
    hi[i] = hh;
    lo[i] = f2bf(x - bf2f(hh));
  }
}

// ---------------- final: mirror symmetric entries ----------------
__global__ __launch_bounds__(256) void sym_fix_k(float* __restrict__ out){
  int i = blockIdx.x*256 + threadIdx.x;   // one (node, channel) per thread
  if (i < NN*16){
    float* op = out + (size_t)i*9;
    float a = op[1], b = op[2], c = op[5];
    op[3] = a; op[6] = b; op[7] = c;
  }
}

// ---------------- Kernel A: tensor_init (all-f32, verified) ----------------
__global__ __launch_bounds__(256) void tensor_init_k(
    const float* __restrict__ h,
    const float* __restrict__ W1, const float* __restrict__ b1,
    const float* __restrict__ g1, const float* __restrict__ be1,
    const float* __restrict__ W2, const float* __restrict__ b2,
    const float* __restrict__ g2, const float* __restrict__ be2,
    float* __restrict__ tout)
{
    __shared__ float h_s[4][128];
    __shared__ float t_s[4][160];
    const int w = threadIdx.x >> 6;
    const int l = threadIdx.x & 63;
    const int n = blockIdx.x * 4 + w;

    h_s[w][l]      = h[n * HD + l];
    h_s[w][l + 64] = h[n * HD + l + 64];
    __syncthreads();

    const int j0 = l, j1 = 64 + l, j2 = 128 + (l & 15);

    float a0 = 0.f, a1 = 0.f, a2 = 0.f;
    {
        const float4* r0 = (const float4*)(W1 + j0 * HD);
        const float4* r1 = (const float4*)(W1 + j1 * HD);
        const float4* r2 = (const float4*)(W1 + j2 * HD);
        const float4* hv = (const float4*)(&h_s[w][0]);
        #pragma unroll 8
        for (int kq = 0; kq < HD / 4; ++kq) {
            float4 hq = hv[kq];
            float4 x0 = r0[kq]; a0 += x0.x*hq.x + x0.y*hq.y + x0.z*hq.z + x0.w*hq.w;
            float4 x1 = r1[kq]; a1 += x1.x*hq.x + x1.y*hq.y + x1.z*hq.z + x1.w*hq.w;
            float4 x2 = r2[kq]; a2 += x2.x*hq.x + x2.y*hq.y + x2.z*hq.z + x2.w*hq.w;
        }
    }
    a0 += b1[j0]; a1 += b1[j1]; a2 += b1[j2];
    {
        float m2 = (l < 16) ? a2 : 0.f;
        float s = a0 + a1 + m2;
        float q = a0*a0 + a1*a1 + m2*m2;
        #pragma unroll
        for (int off = 32; off >= 1; off >>= 1) { s += __shfl_xor(s, off); q += __shfl_xor(q, off); }
        float mu = s * (1.0f / 144.0f);
        float rs = rsqrtf(q * (1.0f / 144.0f) - mu * mu + 1e-5f);
        t_s[w][j0] = siluf_((a0 - mu) * rs * g1[j0] + be1[j0]);
        t_s[w][j1] = siluf_((a1 - mu) * rs * g1[j1] + be1[j1]);
        if (l < 16) t_s[w][j2] = siluf_((a2 - mu) * rs * g1[j2] + be1[j2]);
    }
    __syncthreads();

    a0 = a1 = a2 = 0.f;
    {
        const float4* r0 = (const float4*)(W2 + j0 * D9);
        const float4* r1 = (const float4*)(W2 + j1 * D9);
        const float4* r2 = (const float4*)(W2 + j2 * D9);
        const float4* tv = (const float4*)(&t_s[w][0]);
        #pragma unroll 6
        for (int kq = 0; kq < D9 / 4; ++kq) {
            float4 hq = tv[kq];
            float4 x0 = r0[kq]; a0 += x0.x*hq.x + x0.y*hq.y + x0.z*hq.z + x0.w*hq.w;
            float4 x1 = r1[kq]; a1 += x1.x*hq.x + x1.y*hq.y + x1.z*hq.z + x1.w*hq.w;
            float4 x2 = r2[kq]; a2 += x2.x*hq.x + x2.y*hq.y + x2.z*hq.z + x2.w*hq.w;
        }
    }
    a0 += b2[j0]; a1 += b2[j1]; a2 += b2[j2];
    {
        float m2 = (l < 16) ? a2 : 0.f;
        float s = a0 + a1 + m2;
        float q = a0*a0 + a1*a1 + m2*m2;
        #pragma unroll
        for (int off = 32; off >= 1; off >>= 1) { s += __shfl_xor(s, off); q += __shfl_xor(q, off); }
        float mu = s * (1.0f / 144.0f);
        float rs = rsqrtf(q * (1.0f / 144.0f) - mu * mu + 1e-5f);
        tout[n * D9 + j0] = siluf_((a0 - mu) * rs * g2[j0] + be2[j0]);
        tout[n * D9 + j1] = siluf_((a1 - mu) * rs * g2[j1] + be2[j1]);
        if (l < 16) tout[n * D9 + j2] = siluf_((a2 - mu) * rs * g2[j2] + be2[j2]);
    }
}

// ---------------- Kernel B: edges ----------------
// 16 edges/block, 256 threads (4 waves). LDS ~34 KB -> 4 blocks/CU.
// bf16x3-split MFMA GEMM (fp32-equivalent) -> f32 LN/sigmoid -> f32 wbuf.
// Rotation results stay in registers; contraction consumes them via
// width-16 shuffles (no st[] LDS buffer). 6 atomics per (edge,channel).
#define WLO 131072   // element offset of W_lo within Wspl
#define WST 520      // wbuf edge stride (f32): 520 % 32 = 8 -> 2-way max
__global__ __launch_bounds__(256) void edge_k(
    const float* __restrict__ h,
    const float* __restrict__ frames,
    const int* __restrict__ ei,
    const float* __restrict__ tens,
    const u16* __restrict__ Wspl,
    const float* __restrict__ bi, const float* __restrict__ gi, const float* __restrict__ bei,
    float* __restrict__ out)
{
  __shared__ __align__(16) float wbuf[16 * WST];  // w[e][512] f32
  __shared__ int ei_s[32];                        // [0..15]=row, [16..31]=col
  __shared__ float pool[160];                     // LN red/mu/rs; reused as rrel[0..143]

  const int t  = threadIdx.x;
  const int w  = t >> 6;
  const int l  = t & 63;
  const int lr = l & 15;
  const int lg = l >> 4;
  const int eb = blockIdx.x * 16;

  if (t < 16)      { int v = ei[eb + t];          ei_s[t] = v < 0 ? 0 : (v >= NN ? NN - 1 : v); }  // row
  else if (t < 32) { int v = ei[EE + eb + (t-16)]; ei_s[t] = v < 0 ? 0 : (v >= NN ? NN - 1 : v); } // col
  __syncthreads();

  // ================= GEMM: z[16 x 512] = [hi|hj] @ Wi^T (bf16x3 MFMA) =================
  const float* qAc = h + (size_t)ei_s[16 + lr] * HD + lg*8;  // hi = h[col]  (k < 128)
  const float* qAr = h + (size_t)ei_s[lr]      * HD + lg*8;  // hj = h[row]  (k >= 128)
  const u16* pB[8];
  #pragma unroll
  for (int nt = 0; nt < 8; ++nt)
    pB[nt] = Wspl + (size_t)(w*128 + nt*16 + lr) * 256 + lg*8;

  f32x4 acc[8];
  #pragma unroll
  for (int nt = 0; nt < 8; ++nt) acc[nt] = (f32x4){0.f, 0.f, 0.f, 0.f};

  #pragma unroll
  for (int ks = 0; ks < 8; ++ks){
    const float* qa = (ks < 4) ? (qAc + ks*32) : (qAr + (ks-4)*32);
    float4 x0 = *(const float4*)qa;
    float4 x1 = *(const float4*)(qa + 4);
    float xs[8] = {x0.x, x0.y, x0.z, x0.w, x1.x, x1.y, x1.z, x1.w};
    short8 aH, aL;
    #pragma unroll
    for (int j = 0; j < 8; ++j){
      u16 hh = f2bf(xs[j]);
      aH[j] = (short)hh;
      aL[j] = (short)f2bf(xs[j] - bf2f(hh));
    }
    #pragma unroll
    for (int nt = 0; nt < 8; ++nt){
      short8 bH = *(const short8*)(pB[nt] + ks*32);
      short8 bL = *(const short8*)(pB[nt] + WLO + ks*32);
      acc[nt] = __builtin_amdgcn_mfma_f32_16x16x32_bf16(aH, bH, acc[nt], 0, 0, 0);
      acc[nt] = __builtin_amdgcn_mfma_f32_16x16x32_bf16(aL, bH, acc[nt], 0, 0, 0);
      acc[nt] = __builtin_amdgcn_mfma_f32_16x16x32_bf16(aH, bL, acc[nt], 0, 0, 0);
    }
  }

  // ================= LayerNorm over 512 per edge + sigmoid (f32) =================
  float biv[8], giv[8], bev[8];
  #pragma unroll
  for (int nt = 0; nt < 8; ++nt){
    int n = w*128 + nt*16 + lr;
    biv[nt] = bi[n]; giv[nt] = gi[n]; bev[nt] = bei[n];
  }
  float zs[4], zq[4];
  #pragma unroll
  for (int r = 0; r < 4; ++r){
    float s = 0.f, q = 0.f;
    #pragma unroll
    for (int nt = 0; nt < 8; ++nt){
      float z = acc[nt][r] + biv[nt];
      s += z; q += z*z;
    }
    zs[r] = s; zq[r] = q;
  }
  #pragma unroll
  for (int off = 1; off < 16; off <<= 1){
    #pragma unroll
    for (int r = 0; r < 4; ++r){
      zs[r] += __shfl_xor(zs[r], off);
      zq[r] += __shfl_xor(zq[r], off);
    }
  }
  if (lr == 0){
    #pragma unroll
    for (int r = 0; r < 4; ++r){
      int e = lg*4 + r;
      pool[w*32 + e*2 + 0] = zs[r];
      pool[w*32 + e*2 + 1] = zq[r];
    }
  }
  __syncthreads();
  if (t < 16){
    float s = pool[t*2]     + pool[32 + t*2]     + pool[64 + t*2]     + pool[96 + t*2];
    float q = pool[t*2 + 1] + pool[32 + t*2 + 1] + pool[64 + t*2 + 1] + pool[96 + t*2 + 1];
    float mu = s * (1.0f / 512.0f);
    pool[128 + t] = mu;
    pool[144 + t] = rsqrtf(q * (1.0f / 512.0f) - mu*mu + 1e-5f);
  }
  __syncthreads();
  #pragma unroll
  for (int r = 0; r < 4; ++r){
    int e = lg*4 + r;
    float mu = pool[128 + e], rs = pool[144 + e];
    #pragma unroll
    for (int nt = 0; nt < 8; ++nt){
      int n = w*128 + nt*16 + lr;
      float z = acc[nt][r] + biv[nt];
      wbuf[e*WST + n] = sigmoidf_((z - mu) * rs * giv[nt] + bev[nt]);
    }
  }
  __syncthreads();   // wbuf ready; pool (red/mu/rs) dead

  // ================= R_rel = Ri^T @ Rj  (pool[0..143]) =================
  if (t < 144){
    int e = t / 9, cc = t - e*9;
    int i = cc / 3, j = cc - i*3;
    const float* Ri = frames + (size_t)ei_s[16 + e] * 9;  // col
    const float* Rj = frames + (size_t)ei_s[e] * 9;       // row
    pool[t] = Ri[i]*Rj[j] + Ri[3+i]*Rj[3+j] + Ri[6+i]*Rj[6+j];
  }
  __syncthreads();

  // ================= rotate tj (registers), contract via shfl =================
  const int e3 = t >> 4;   // edge (block-local); 16-lane group-aligned within wave
  const int c  = t & 15;   // channel
  {
    float R[9];
    #pragma unroll
    for (int m = 0; m < 9; ++m) R[m] = pool[e3*9 + m];

    float TI[9], T[9];
    const float* tip = tens + (size_t)ei_s[16 + e3] * D9 + c*9;  // ti = tensors[col]
    const float* tjp = tens + (size_t)ei_s[e3]      * D9 + c*9;  // tj = tensors[row]
    #pragma unroll
    for (int m = 0; m < 9; ++m) TI[m] = tip[m];
    #pragma unroll
    for (int m = 0; m < 9; ++m) T[m]  = tjp[m];

    // B = R @ T @ R   (einsum 'eik,eckl,elj->ecij')
    float A[9], B[9];
    #pragma unroll
    for (int i = 0; i < 3; ++i)
      #pragma unroll
      for (int j = 0; j < 3; ++j)
        A[i*3+j] = R[i*3+0]*T[0+j] + R[i*3+1]*T[3+j] + R[i*3+2]*T[6+j];
    #pragma unroll
    for (int i = 0; i < 3; ++i)
      #pragma unroll
      for (int j = 0; j < 3; ++j)
        B[i*3+j] = A[i*3+0]*R[0+j] + A[i*3+1]*R[3+j] + A[i*3+2]*R[6+j];

    // contraction: o[m] = sum_k stacked[k][m] * w[k*16+c]
    // lane (e3, k) of this 16-lane group holds TI (k) and B (16+k)
    float o[9];
    #pragma unroll
    for (int m = 0; m < 9; ++m) o[m] = 0.f;
    const float* wp = wbuf + e3*WST + c;
    #pragma unroll
    for (int k = 0; k < 16; ++k){
      float wk = wp[k*16];
      #pragma unroll
      for (int m = 0; m < 9; ++m) o[m] += __shfl(TI[m], k, 16) * wk;
    }
    #pragma unroll
    for (int k = 0; k < 16; ++k){
      float wk = wp[(16 + k)*16];
      #pragma unroll
      for (int m = 0; m < 9; ++m) o[m] += __shfl(B[m], k, 16) * wk;
    }

    // symmetrize (6 unique entries) + scatter
    float s01 = 0.5f*(o[1]+o[3]), s02 = 0.5f*(o[2]+o[6]), s12 = 0.5f*(o[5]+o[7]);
    float* op = out + (size_t)ei_s[16 + e3] * D9 + c*9;
    atomicAdd(op+0, o[0]);
    atomicAdd(op+1, s01);
    atomicAdd(op+2, s02);
    atomicAdd(op+4, o[4]);
    atomicAdd(op+5, s12);
    atomicAdd(op+8, o[8]);
  }
}

extern "C" void kernel_launch(void* const* d_in, const int* in_sizes, int n_in,
                              void* d_out, int out_size, void* d_ws, size_t ws_size,
                              hipStream_t stream) {
    const float* h      = (const float*)d_in[1];
    const float* frames = (const float*)d_in[2];
    const int*   ei     = (const int*)d_in[3];
    const float* W1  = (const float*)d_in[5];
    const float* b1  = (const float*)d_in[6];
    const float* g1  = (const float*)d_in[7];
    const float* be1 = (const float*)d_in[8];
    const float* W2  = (const float*)d_in[9];
    const float* b2  = (const float*)d_in[10];
    const float* g2  = (const float*)d_in[11];
    const float* be2 = (const float*)d_in[12];
    const float* Wi  = (const float*)d_in[13];
    const float* bi  = (const float*)d_in[14];
    const float* gi  = (const float*)d_in[15];
    const float* bei = (const float*)d_in[16];

    float* out = (float*)d_out;

    // ws layout (17.8 MB, within proven budget):
    u16*   Wspl = (u16*)d_ws;                     // [2][512,256] bf16 hi|lo : 524,288 B
    float* tens = (float*)((char*)d_ws + 524288); // [N,144] f32 : 17,280,000 B

    hipMemsetAsync(d_out, 0, (size_t)out_size * sizeof(float), stream);

    cvt_split_k<<<512, 256, 0, stream>>>(Wi, Wspl, Wspl + WLO, 512*256);
    tensor_init_k<<<NN/4, 256, 0, stream>>>(h, W1, b1, g1, be1, W2, b2, g2, be2, tens);
    edge_k<<<EE/16, 256, 0, stream>>>(h, frames, ei, tens, Wspl, bi, gi, bei, out);
    sym_fix_k<<<(NN*16 + 255)/256, 256, 0, stream>>>(out);
}

// Round 6
// 1604.844 us; speedup vs baseline: 1.9951x; 1.3779x over previous
//
#include <hip/hip_runtime.h>

#define NN 30000
#define EE 300000
#define HD 128
#define D9 144

typedef unsigned int uint32;
typedef unsigned short u16;
typedef __attribute__((ext_vector_type(8))) short short8;
typedef __attribute__((ext_vector_type(4))) float f32x4;

__device__ __forceinline__ float sigmoidf_(float x){ return 1.0f/(1.0f+__expf(-x)); }
__device__ __forceinline__ float siluf_(float x){ return x/(1.0f+__expf(-x)); }
__device__ __forceinline__ u16 f2bf(float f){
  uint32 u = __float_as_uint(f);
  return (u16)((u + 0x7fffu + ((u>>16)&1u)) >> 16);   // RNE
}
__device__ __forceinline__ float bf2f(u16 b){ return __uint_as_float(((uint32)b)<<16); }

// ---------------- f32 -> (bf16 hi, bf16 lo) splitter (fallback path) ----------------
__global__ __launch_bounds__(256) void cvt_split_k(const float* __restrict__ src,
                                                   u16* __restrict__ hi, u16* __restrict__ lo, int n){
  int i = blockIdx.x*256 + threadIdx.x;
  if (i < n){
    float x = src[i];
    u16 hh = f2bf(x);
    hi[i] = hh;
    lo[i] = f2bf(x - bf2f(hh));
  }
}

// ---------------- Wi -> [WiL_hi | WiL_lo | WiR_hi | WiR_lo], each [512x128] ----------------
__global__ __launch_bounds__(256) void cvt_wq_k(const float* __restrict__ Wi, u16* __restrict__ Wq){
  int i = blockIdx.x*256 + threadIdx.x;   // over 512*128
  if (i < 512*128){
    int n = i >> 7, k = i & 127;
    float xl = Wi[n*256 + k];
    float xr = Wi[n*256 + 128 + k];
    u16 lh = f2bf(xl);
    Wq[i]          = lh;
    Wq[65536 + i]  = f2bf(xl - bf2f(lh));
    u16 rh = f2bf(xr);
    Wq[131072 + i] = rh;
    Wq[196608 + i] = f2bf(xr - bf2f(rh));
  }
}

// ---------------- final: mirror symmetric entries ----------------
__global__ __launch_bounds__(256) void sym_fix_k(float* __restrict__ out){
  int i = blockIdx.x*256 + threadIdx.x;   // one (node, channel) per thread
  if (i < NN*16){
    float* op = out + (size_t)i*9;
    float a = op[1], b = op[2], c = op[5];
    op[3] = a; op[6] = b; op[7] = c;
  }
}

// ---------------- Kernel A: tensor_init (all-f32, verified) ----------------
__global__ __launch_bounds__(256) void tensor_init_k(
    const float* __restrict__ h,
    const float* __restrict__ W1, const float* __restrict__ b1,
    const float* __restrict__ g1, const float* __restrict__ be1,
    const float* __restrict__ W2, const float* __restrict__ b2,
    const float* __restrict__ g2, const float* __restrict__ be2,
    float* __restrict__ tout)
{
    __shared__ float h_s[4][128];
    __shared__ float t_s[4][160];
    const int w = threadIdx.x >> 6;
    const int l = threadIdx.x & 63;
    const int n = blockIdx.x * 4 + w;

    h_s[w][l]      = h[n * HD + l];
    h_s[w][l + 64] = h[n * HD + l + 64];
    __syncthreads();

    const int j0 = l, j1 = 64 + l, j2 = 128 + (l & 15);

    float a0 = 0.f, a1 = 0.f, a2 = 0.f;
    {
        const float4* r0 = (const float4*)(W1 + j0 * HD);
        const float4* r1 = (const float4*)(W1 + j1 * HD);
        const float4* r2 = (const float4*)(W1 + j2 * HD);
        const float4* hv = (const float4*)(&h_s[w][0]);
        #pragma unroll 8
        for (int kq = 0; kq < HD / 4; ++kq) {
            float4 hq = hv[kq];
            float4 x0 = r0[kq]; a0 += x0.x*hq.x + x0.y*hq.y + x0.z*hq.z + x0.w*hq.w;
            float4 x1 = r1[kq]; a1 += x1.x*hq.x + x1.y*hq.y + x1.z*hq.z + x1.w*hq.w;
            float4 x2 = r2[kq]; a2 += x2.x*hq.x + x2.y*hq.y + x2.z*hq.z + x2.w*hq.w;
        }
    }
    a0 += b1[j0]; a1 += b1[j1]; a2 += b1[j2];
    {
        float m2 = (l < 16) ? a2 : 0.f;
        float s = a0 + a1 + m2;
        float q = a0*a0 + a1*a1 + m2*m2;
        #pragma unroll
        for (int off = 32; off >= 1; off >>= 1) { s += __shfl_xor(s, off); q += __shfl_xor(q, off); }
        float mu = s * (1.0f / 144.0f);
        float rs = rsqrtf(q * (1.0f / 144.0f) - mu * mu + 1e-5f);
        t_s[w][j0] = siluf_((a0 - mu) * rs * g1[j0] + be1[j0]);
        t_s[w][j1] = siluf_((a1 - mu) * rs * g1[j1] + be1[j1]);
        if (l < 16) t_s[w][j2] = siluf_((a2 - mu) * rs * g1[j2] + be1[j2]);
    }
    __syncthreads();

    a0 = a1 = a2 = 0.f;
    {
        const float4* r0 = (const float4*)(W2 + j0 * D9);
        const float4* r1 = (const float4*)(W2 + j1 * D9);
        const float4* r2 = (const float4*)(W2 + j2 * D9);
        const float4* tv = (const float4*)(&t_s[w][0]);
        #pragma unroll 6
        for (int kq = 0; kq < D9 / 4; ++kq) {
            float4 hq = tv[kq];
            float4 x0 = r0[kq]; a0 += x0.x*hq.x + x0.y*hq.y + x0.z*hq.z + x0.w*hq.w;
            float4 x1 = r1[kq]; a1 += x1.x*hq.x + x1.y*hq.y + x1.z*hq.z + x1.w*hq.w;
            float4 x2 = r2[kq]; a2 += x2.x*hq.x + x2.y*hq.y + x2.z*hq.z + x2.w*hq.w;
        }
    }
    a0 += b2[j0]; a1 += b2[j1]; a2 += b2[j2];
    {
        float m2 = (l < 16) ? a2 : 0.f;
        float s = a0 + a1 + m2;
        float q = a0*a0 + a1*a1 + m2*m2;
        #pragma unroll
        for (int off = 32; off >= 1; off >>= 1) { s += __shfl_xor(s, off); q += __shfl_xor(q, off); }
        float mu = s * (1.0f / 144.0f);
        float rs = rsqrtf(q * (1.0f / 144.0f) - mu * mu + 1e-5f);
        tout[n * D9 + j0] = siluf_((a0 - mu) * rs * g2[j0] + be2[j0]);
        tout[n * D9 + j1] = siluf_((a1 - mu) * rs * g2[j1] + be2[j1]);
        if (l < 16) tout[n * D9 + j2] = siluf_((a2 - mu) * rs * g2[j2] + be2[j2]);
    }
}

// ================== NEW PATH ==================
// node_gemm_k: u[n] = WiL @ h[n] + bi, v[n] = WiR @ h[n]  (bf16x3-split MFMA)
// 16 nodes/block, 256 threads (4 waves); wave w owns n in [w*128, (w+1)*128).
__global__ __launch_bounds__(256) void node_gemm_k(
    const float* __restrict__ h, const u16* __restrict__ Wq,
    const float* __restrict__ bi,
    float* __restrict__ u, float* __restrict__ v)
{
  const int t = threadIdx.x;
  const int w = t >> 6, l = t & 63, lr = l & 15, lg = l >> 4;
  const int nb = blockIdx.x * 16;

  const float* qA = h + (size_t)(nb + lr) * HD + lg*8;
  const u16* bu[8]; const u16* bv[8];
  #pragma unroll
  for (int nt = 0; nt < 8; ++nt){
    int n = w*128 + nt*16 + lr;
    bu[nt] = Wq + n*128 + lg*8;            // WiL_hi (lo at +65536)
    bv[nt] = Wq + 131072 + n*128 + lg*8;   // WiR_hi (lo at +65536)
  }

  f32x4 au[8], av[8];
  #pragma unroll
  for (int nt = 0; nt < 8; ++nt){ au[nt] = (f32x4){0,0,0,0}; av[nt] = (f32x4){0,0,0,0}; }

  #pragma unroll
  for (int ks = 0; ks < 4; ++ks){
    float4 x0 = *(const float4*)(qA + ks*32);
    float4 x1 = *(const float4*)(qA + ks*32 + 4);
    float xs[8] = {x0.x, x0.y, x0.z, x0.w, x1.x, x1.y, x1.z, x1.w};
    short8 aH, aL;
    #pragma unroll
    for (int j = 0; j < 8; ++j){
      u16 hh = f2bf(xs[j]);
      aH[j] = (short)hh;
      aL[j] = (short)f2bf(xs[j] - bf2f(hh));
    }
    #pragma unroll
    for (int nt = 0; nt < 8; ++nt){
      short8 bH = *(const short8*)(bu[nt] + ks*32);
      short8 bL = *(const short8*)(bu[nt] + 65536 + ks*32);
      au[nt] = __builtin_amdgcn_mfma_f32_16x16x32_bf16(aH, bH, au[nt], 0, 0, 0);
      au[nt] = __builtin_amdgcn_mfma_f32_16x16x32_bf16(aL, bH, au[nt], 0, 0, 0);
      au[nt] = __builtin_amdgcn_mfma_f32_16x16x32_bf16(aH, bL, au[nt], 0, 0, 0);
      short8 cH = *(const short8*)(bv[nt] + ks*32);
      short8 cL = *(const short8*)(bv[nt] + 65536 + ks*32);
      av[nt] = __builtin_amdgcn_mfma_f32_16x16x32_bf16(aH, cH, av[nt], 0, 0, 0);
      av[nt] = __builtin_amdgcn_mfma_f32_16x16x32_bf16(aL, cH, av[nt], 0, 0, 0);
      av[nt] = __builtin_amdgcn_mfma_f32_16x16x32_bf16(aH, cL, av[nt], 0, 0, 0);
    }
  }

  // C layout (verified): col(lane&15)=n-within-tile, row=(lane>>4)*4+r = node-within-block
  #pragma unroll
  for (int nt = 0; nt < 8; ++nt){
    int n = w*128 + nt*16 + lr;
    float bb = bi[n];
    #pragma unroll
    for (int r = 0; r < 4; ++r){
      size_t node = nb + lg*4 + r;
      u[node*512 + n] = au[nt][r] + bb;
      v[node*512 + n] = av[nt][r];
    }
  }
}

// edge_k2: barrier-free, LDS-free edge kernel.
// Thread (e3, c) owns edge e3 of the block, channel c. It gathers exactly the
// z-values n = k*16+c (k=0..31) that its contraction needs; LN via 16-lane shfl.
__global__ __launch_bounds__(256) void edge_k2(
    const float* __restrict__ u, const float* __restrict__ v,
    const float* __restrict__ frames, const int* __restrict__ ei,
    const float* __restrict__ tens,
    const float* __restrict__ gi, const float* __restrict__ bei,
    float* __restrict__ out)
{
  const int t  = threadIdx.x;
  const int e3 = t >> 4, c = t & 15;
  const int e  = blockIdx.x * 16 + e3;
  int row = ei[e];        row = row < 0 ? 0 : (row >= NN ? NN-1 : row);
  int col = ei[EE + e];   col = col < 0 ? 0 : (col >= NN ? NN-1 : col);

  // ---- z[k] = u[col][k*16+c] + v[row][k*16+c] ----
  const float* up = u + (size_t)col*512 + c;
  const float* vp = v + (size_t)row*512 + c;
  float z[32];
  #pragma unroll
  for (int k = 0; k < 32; ++k) z[k] = up[k*16] + vp[k*16];

  // ---- LayerNorm stats over 512 (32 per lane x 16 lanes) ----
  float s = 0.f, q = 0.f;
  #pragma unroll
  for (int k = 0; k < 32; ++k){ s += z[k]; q += z[k]*z[k]; }
  #pragma unroll
  for (int off = 1; off < 16; off <<= 1){ s += __shfl_xor(s, off); q += __shfl_xor(q, off); }
  float mu = s * (1.0f/512.0f);
  float rs = rsqrtf(q * (1.0f/512.0f) - mu*mu + 1e-5f);

  // ---- w[k] = sigmoid(LN(z)) (in place) ----
  const float* gp = gi  + c;
  const float* bp = bei + c;
  #pragma unroll
  for (int k = 0; k < 32; ++k)
    z[k] = sigmoidf_((z[k] - mu) * rs * gp[k*16] + bp[k*16]);

  // ---- R_rel = Ri^T @ Rj (per-thread, redundant x16 — broadcast loads) ----
  const float* Ri = frames + (size_t)col*9;
  const float* Rj = frames + (size_t)row*9;
  float R[9];
  #pragma unroll
  for (int i = 0; i < 3; ++i)
    #pragma unroll
    for (int j = 0; j < 3; ++j)
      R[i*3+j] = Ri[i]*Rj[j] + Ri[3+i]*Rj[3+j] + Ri[6+i]*Rj[6+j];

  // ---- tensors ----
  float TI[9], T[9];
  const float* tip = tens + (size_t)col*D9 + c*9;
  const float* tjp = tens + (size_t)row*D9 + c*9;
  #pragma unroll
  for (int m = 0; m < 9; ++m) TI[m] = tip[m];
  #pragma unroll
  for (int m = 0; m < 9; ++m) T[m]  = tjp[m];

  // B = R @ T @ R   (einsum 'eik,eckl,elj->ecij')
  float A[9], B[9];
  #pragma unroll
  for (int i = 0; i < 3; ++i)
    #pragma unroll
    for (int j = 0; j < 3; ++j)
      A[i*3+j] = R[i*3+0]*T[0+j] + R[i*3+1]*T[3+j] + R[i*3+2]*T[6+j];
  #pragma unroll
  for (int i = 0; i < 3; ++i)
    #pragma unroll
    for (int j = 0; j < 3; ++j)
      B[i*3+j] = A[i*3+0]*R[0+j] + A[i*3+1]*R[3+j] + A[i*3+2]*R[6+j];

  // ---- contraction: o[m] = sum_k stacked[k][m] * w[k] (lane k holds channel k) ----
  float o[9];
  #pragma unroll
  for (int m = 0; m < 9; ++m) o[m] = 0.f;
  #pragma unroll
  for (int k = 0; k < 16; ++k){
    float wk = z[k];
    #pragma unroll
    for (int m = 0; m < 9; ++m) o[m] += __shfl(TI[m], k, 16) * wk;
  }
  #pragma unroll
  for (int k = 0; k < 16; ++k){
    float wk = z[16 + k];
    #pragma unroll
    for (int m = 0; m < 9; ++m) o[m] += __shfl(B[m], k, 16) * wk;
  }

  // ---- symmetrize (6 unique) + scatter ----
  float s01 = 0.5f*(o[1]+o[3]), s02 = 0.5f*(o[2]+o[6]), s12 = 0.5f*(o[5]+o[7]);
  float* op = out + (size_t)col * D9 + c*9;
  atomicAdd(op+0, o[0]);
  atomicAdd(op+1, s01);
  atomicAdd(op+2, s02);
  atomicAdd(op+4, o[4]);
  atomicAdd(op+5, s12);
  atomicAdd(op+8, o[8]);
}

// ================== FALLBACK PATH (round-5, proven) ==================
#define WLO 131072
#define WST 520
__global__ __launch_bounds__(256) void edge_k(
    const float* __restrict__ h,
    const float* __restrict__ frames,
    const int* __restrict__ ei,
    const float* __restrict__ tens,
    const u16* __restrict__ Wspl,
    const float* __restrict__ bi, const float* __restrict__ gi, const float* __restrict__ bei,
    float* __restrict__ out)
{
  __shared__ __align__(16) float wbuf[16 * WST];
  __shared__ int ei_s[32];
  __shared__ float pool[160];

  const int t  = threadIdx.x;
  const int w  = t >> 6;
  const int l  = t & 63;
  const int lr = l & 15;
  const int lg = l >> 4;
  const int eb = blockIdx.x * 16;

  if (t < 16)      { int v = ei[eb + t];          ei_s[t] = v < 0 ? 0 : (v >= NN ? NN - 1 : v); }
  else if (t < 32) { int v = ei[EE + eb + (t-16)]; ei_s[t] = v < 0 ? 0 : (v >= NN ? NN - 1 : v); }
  __syncthreads();

  const float* qAc = h + (size_t)ei_s[16 + lr] * HD + lg*8;
  const float* qAr = h + (size_t)ei_s[lr]      * HD + lg*8;
  const u16* pB[8];
  #pragma unroll
  for (int nt = 0; nt < 8; ++nt)
    pB[nt] = Wspl + (size_t)(w*128 + nt*16 + lr) * 256 + lg*8;

  f32x4 acc[8];
  #pragma unroll
  for (int nt = 0; nt < 8; ++nt) acc[nt] = (f32x4){0.f, 0.f, 0.f, 0.f};

  #pragma unroll
  for (int ks = 0; ks < 8; ++ks){
    const float* qa = (ks < 4) ? (qAc + ks*32) : (qAr + (ks-4)*32);
    float4 x0 = *(const float4*)qa;
    float4 x1 = *(const float4*)(qa + 4);
    float xs[8] = {x0.x, x0.y, x0.z, x0.w, x1.x, x1.y, x1.z, x1.w};
    short8 aH, aL;
    #pragma unroll
    for (int j = 0; j < 8; ++j){
      u16 hh = f2bf(xs[j]);
      aH[j] = (short)hh;
      aL[j] = (short)f2bf(xs[j] - bf2f(hh));
    }
    #pragma unroll
    for (int nt = 0; nt < 8; ++nt){
      short8 bH = *(const short8*)(pB[nt] + ks*32);
      short8 bL = *(const short8*)(pB[nt] + WLO + ks*32);
      acc[nt] = __builtin_amdgcn_mfma_f32_16x16x32_bf16(aH, bH, acc[nt], 0, 0, 0);
      acc[nt] = __builtin_amdgcn_mfma_f32_16x16x32_bf16(aL, bH, acc[nt], 0, 0, 0);
      acc[nt] = __builtin_amdgcn_mfma_f32_16x16x32_bf16(aH, bL, acc[nt], 0, 0, 0);
    }
  }

  float biv[8], giv[8], bev[8];
  #pragma unroll
  for (int nt = 0; nt < 8; ++nt){
    int n = w*128 + nt*16 + lr;
    biv[nt] = bi[n]; giv[nt] = gi[n]; bev[nt] = bei[n];
  }
  float zs[4], zq[4];
  #pragma unroll
  for (int r = 0; r < 4; ++r){
    float s = 0.f, q = 0.f;
    #pragma unroll
    for (int nt = 0; nt < 8; ++nt){
      float z = acc[nt][r] + biv[nt];
      s += z; q += z*z;
    }
    zs[r] = s; zq[r] = q;
  }
  #pragma unroll
  for (int off = 1; off < 16; off <<= 1){
    #pragma unroll
    for (int r = 0; r < 4; ++r){
      zs[r] += __shfl_xor(zs[r], off);
      zq[r] += __shfl_xor(zq[r], off);
    }
  }
  if (lr == 0){
    #pragma unroll
    for (int r = 0; r < 4; ++r){
      int e = lg*4 + r;
      pool[w*32 + e*2 + 0] = zs[r];
      pool[w*32 + e*2 + 1] = zq[r];
    }
  }
  __syncthreads();
  if (t < 16){
    float s = pool[t*2]     + pool[32 + t*2]     + pool[64 + t*2]     + pool[96 + t*2];
    float q = pool[t*2 + 1] + pool[32 + t*2 + 1] + pool[64 + t*2 + 1] + pool[96 + t*2 + 1];
    float mu = s * (1.0f / 512.0f);
    pool[128 + t] = mu;
    pool[144 + t] = rsqrtf(q * (1.0f / 512.0f) - mu*mu + 1e-5f);
  }
  __syncthreads();
  #pragma unroll
  for (int r = 0; r < 4; ++r){
    int e = lg*4 + r;
    float mu = pool[128 + e], rs = pool[144 + e];
    #pragma unroll
    for (int nt = 0; nt < 8; ++nt){
      int n = w*128 + nt*16 + lr;
      float z = acc[nt][r] + biv[nt];
      wbuf[e*WST + n] = sigmoidf_((z - mu) * rs * giv[nt] + bev[nt]);
    }
  }
  __syncthreads();

  if (t < 144){
    int e = t / 9, cc = t - e*9;
    int i = cc / 3, j = cc - i*3;
    const float* Ri = frames + (size_t)ei_s[16 + e] * 9;
    const float* Rj = frames + (size_t)ei_s[e] * 9;
    pool[t] = Ri[i]*Rj[j] + Ri[3+i]*Rj[3+j] + Ri[6+i]*Rj[6+j];
  }
  __syncthreads();

  const int e3 = t >> 4;
  const int c  = t & 15;
  {
    float R[9];
    #pragma unroll
    for (int m = 0; m < 9; ++m) R[m] = pool[e3*9 + m];

    float TI[9], T[9];
    const float* tip = tens + (size_t)ei_s[16 + e3] * D9 + c*9;
    const float* tjp = tens + (size_t)ei_s[e3]      * D9 + c*9;
    #pragma unroll
    for (int m = 0; m < 9; ++m) TI[m] = tip[m];
    #pragma unroll
    for (int m = 0; m < 9; ++m) T[m]  = tjp[m];

    float A[9], B[9];
    #pragma unroll
    for (int i = 0; i < 3; ++i)
      #pragma unroll
      for (int j = 0; j < 3; ++j)
        A[i*3+j] = R[i*3+0]*T[0+j] + R[i*3+1]*T[3+j] + R[i*3+2]*T[6+j];
    #pragma unroll
    for (int i = 0; i < 3; ++i)
      #pragma unroll
      for (int j = 0; j < 3; ++j)
        B[i*3+j] = A[i*3+0]*R[0+j] + A[i*3+1]*R[3+j] + A[i*3+2]*R[6+j];

    float o[9];
    #pragma unroll
    for (int m = 0; m < 9; ++m) o[m] = 0.f;
    const float* wp = wbuf + e3*WST + c;
    #pragma unroll
    for (int k = 0; k < 16; ++k){
      float wk = wp[k*16];
      #pragma unroll
      for (int m = 0; m < 9; ++m) o[m] += __shfl(TI[m], k, 16) * wk;
    }
    #pragma unroll
    for (int k = 0; k < 16; ++k){
      float wk = wp[(16 + k)*16];
      #pragma unroll
      for (int m = 0; m < 9; ++m) o[m] += __shfl(B[m], k, 16) * wk;
    }

    float s01 = 0.5f*(o[1]+o[3]), s02 = 0.5f*(o[2]+o[6]), s12 = 0.5f*(o[5]+o[7]);
    float* op = out + (size_t)ei_s[16 + e3] * D9 + c*9;
    atomicAdd(op+0, o[0]);
    atomicAdd(op+1, s01);
    atomicAdd(op+2, s02);
    atomicAdd(op+4, o[4]);
    atomicAdd(op+5, s12);
    atomicAdd(op+8, o[8]);
  }
}

extern "C" void kernel_launch(void* const* d_in, const int* in_sizes, int n_in,
                              void* d_out, int out_size, void* d_ws, size_t ws_size,
                              hipStream_t stream) {
    const float* h      = (const float*)d_in[1];
    const float* frames = (const float*)d_in[2];
    const int*   ei     = (const int*)d_in[3];
    const float* W1  = (const float*)d_in[5];
    const float* b1  = (const float*)d_in[6];
    const float* g1  = (const float*)d_in[7];
    const float* be1 = (const float*)d_in[8];
    const float* W2  = (const float*)d_in[9];
    const float* b2  = (const float*)d_in[10];
    const float* g2  = (const float*)d_in[11];
    const float* be2 = (const float*)d_in[12];
    const float* Wi  = (const float*)d_in[13];
    const float* bi  = (const float*)d_in[14];
    const float* gi  = (const float*)d_in[15];
    const float* bei = (const float*)d_in[16];

    float* out = (float*)d_out;

    hipMemsetAsync(d_out, 0, (size_t)out_size * sizeof(float), stream);

    if (ws_size >= 140684288ull) {
        // ---- NEW PATH: node-level GEMM factorization ----
        // ws: u[30000x512] f32 | v[30000x512] f32 | tens[30000x144] f32 | Wq 4x[512x128] bf16
        float* u    = (float*)d_ws;
        float* v    = (float*)((char*)d_ws + 61440000);
        float* tens = (float*)((char*)d_ws + 122880000);
        u16*   Wq   = (u16*)  ((char*)d_ws + 140160000);

        cvt_wq_k<<<256, 256, 0, stream>>>(Wi, Wq);
        tensor_init_k<<<NN/4, 256, 0, stream>>>(h, W1, b1, g1, be1, W2, b2, g2, be2, tens);
        node_gemm_k<<<NN/16, 256, 0, stream>>>(h, Wq, bi, u, v);
        edge_k2<<<EE/16, 256, 0, stream>>>(u, v, frames, ei, tens, gi, bei, out);
        sym_fix_k<<<(NN*16 + 255)/256, 256, 0, stream>>>(out);
    } else {
        // ---- FALLBACK: round-5 proven path ----
        u16*   Wspl = (u16*)d_ws;
        float* tens = (float*)((char*)d_ws + 524288);

        cvt_split_k<<<512, 256, 0, stream>>>(Wi, Wspl, Wspl + WLO, 512*256);
        tensor_init_k<<<NN/4, 256, 0, stream>>>(h, W1, b1, g1, be1, W2, b2, g2, be2, tens);
        edge_k<<<EE/16, 256, 0, stream>>>(h, frames, ei, tens, Wspl, bi, gi, bei, out);
        sym_fix_k<<<(NN*16 + 255)/256, 256, 0, stream>>>(out);
    }
}

// Round 7
// 1295.134 us; speedup vs baseline: 2.4722x; 1.2391x over previous
//
#include <hip/hip_runtime.h>

#define NN 30000
#define EE 300000
#define HD 128
#define D9 144

typedef unsigned int uint32;
typedef unsigned short u16;
typedef __attribute__((ext_vector_type(8))) short short8;
typedef __attribute__((ext_vector_type(4))) float f32x4;

__device__ __forceinline__ float sigmoidf_(float x){ return 1.0f/(1.0f+__expf(-x)); }
__device__ __forceinline__ float siluf_(float x){ return x/(1.0f+__expf(-x)); }
__device__ __forceinline__ u16 f2bf(float f){
  uint32 u = __float_as_uint(f);
  return (u16)((u + 0x7fffu + ((u>>16)&1u)) >> 16);   // RNE
}
__device__ __forceinline__ float bf2f(u16 b){ return __uint_as_float(((uint32)b)<<16); }

// ---------------- Wi -> [WiL_hi | WiL_lo | WiR_hi | WiR_lo], each [512x128] ----------------
__global__ __launch_bounds__(256) void cvt_wq_k(const float* __restrict__ Wi, u16* __restrict__ Wq){
  int i = blockIdx.x*256 + threadIdx.x;   // over 512*128
  if (i < 512*128){
    int n = i >> 7, k = i & 127;
    float xl = Wi[n*256 + k];
    float xr = Wi[n*256 + 128 + k];
    u16 lh = f2bf(xl);
    Wq[i]          = lh;
    Wq[65536 + i]  = f2bf(xl - bf2f(lh));
    u16 rh = f2bf(xr);
    Wq[131072 + i] = rh;
    Wq[196608 + i] = f2bf(xr - bf2f(rh));
  }
}

// ---------------- CSR build: hist -> scan -> scatter ----------------
__global__ __launch_bounds__(256) void hist_k(const int* __restrict__ ei, uint32* __restrict__ start){
  int e = blockIdx.x*256 + threadIdx.x;
  if (e < EE){
    int col = ei[EE + e];
    col = col < 0 ? 0 : (col >= NN ? NN-1 : col);
    atomicAdd(&start[col], 1u);
  }
}

__global__ __launch_bounds__(1024) void scan_k(uint32* __restrict__ start){
  __shared__ uint32 part[1024];
  const int t = threadIdx.x;
  const int base = t * 30;                 // 1024*30 = 30720 >= NN
  uint32 loc[30];
  uint32 s = 0;
  #pragma unroll
  for (int i = 0; i < 30; ++i){
    int idx = base + i;
    uint32 cv = (idx < NN) ? start[idx] : 0u;
    loc[i] = s;                            // local exclusive prefix
    s += cv;
  }
  part[t] = s;
  __syncthreads();
  for (int off = 1; off < 1024; off <<= 1){
    uint32 add = (t >= off) ? part[t - off] : 0u;
    __syncthreads();
    part[t] += add;
    __syncthreads();
  }
  uint32 pre = (t == 0) ? 0u : part[t - 1];
  #pragma unroll
  for (int i = 0; i < 30; ++i){
    int idx = base + i;
    if (idx < NN) start[idx] = pre + loc[i];
  }
}

__global__ __launch_bounds__(256) void scatter_k(const int* __restrict__ ei,
                                                 uint32* __restrict__ start,
                                                 u16* __restrict__ srow){
  int e = blockIdx.x*256 + threadIdx.x;
  if (e < EE){
    int row = ei[e];
    row = row < 0 ? 0 : (row >= NN ? NN-1 : row);
    int col = ei[EE + e];
    col = col < 0 ? 0 : (col >= NN ? NN-1 : col);
    uint32 pos = atomicAdd(&start[col], 1u);   // start becomes end(col) afterwards
    srow[pos] = (u16)row;
  }
}

// ---------------- Kernel A: tensor_init (all-f32, verified) ----------------
__global__ __launch_bounds__(256) void tensor_init_k(
    const float* __restrict__ h,
    const float* __restrict__ W1, const float* __restrict__ b1,
    const float* __restrict__ g1, const float* __restrict__ be1,
    const float* __restrict__ W2, const float* __restrict__ b2,
    const float* __restrict__ g2, const float* __restrict__ be2,
    float* __restrict__ tout)
{
    __shared__ float h_s[4][128];
    __shared__ float t_s[4][160];
    const int w = threadIdx.x >> 6;
    const int l = threadIdx.x & 63;
    const int n = blockIdx.x * 4 + w;

    h_s[w][l]      = h[n * HD + l];
    h_s[w][l + 64] = h[n * HD + l + 64];
    __syncthreads();

    const int j0 = l, j1 = 64 + l, j2 = 128 + (l & 15);

    float a0 = 0.f, a1 = 0.f, a2 = 0.f;
    {
        const float4* r0 = (const float4*)(W1 + j0 * HD);
        const float4* r1 = (const float4*)(W1 + j1 * HD);
        const float4* r2 = (const float4*)(W1 + j2 * HD);
        const float4* hv = (const float4*)(&h_s[w][0]);
        #pragma unroll 8
        for (int kq = 0; kq < HD / 4; ++kq) {
            float4 hq = hv[kq];
            float4 x0 = r0[kq]; a0 += x0.x*hq.x + x0.y*hq.y + x0.z*hq.z + x0.w*hq.w;
            float4 x1 = r1[kq]; a1 += x1.x*hq.x + x1.y*hq.y + x1.z*hq.z + x1.w*hq.w;
            float4 x2 = r2[kq]; a2 += x2.x*hq.x + x2.y*hq.y + x2.z*hq.z + x2.w*hq.w;
        }
    }
    a0 += b1[j0]; a1 += b1[j1]; a2 += b1[j2];
    {
        float m2 = (l < 16) ? a2 : 0.f;
        float s = a0 + a1 + m2;
        float q = a0*a0 + a1*a1 + m2*m2;
        #pragma unroll
        for (int off = 32; off >= 1; off >>= 1) { s += __shfl_xor(s, off); q += __shfl_xor(q, off); }
        float mu = s * (1.0f / 144.0f);
        float rs = rsqrtf(q * (1.0f / 144.0f) - mu * mu + 1e-5f);
        t_s[w][j0] = siluf_((a0 - mu) * rs * g1[j0] + be1[j0]);
        t_s[w][j1] = siluf_((a1 - mu) * rs * g1[j1] + be1[j1]);
        if (l < 16) t_s[w][j2] = siluf_((a2 - mu) * rs * g1[j2] + be1[j2]);
    }
    __syncthreads();

    a0 = a1 = a2 = 0.f;
    {
        const float4* r0 = (const float4*)(W2 + j0 * D9);
        const float4* r1 = (const float4*)(W2 + j1 * D9);
        const float4* r2 = (const float4*)(W2 + j2 * D9);
        const float4* tv = (const float4*)(&t_s[w][0]);
        #pragma unroll 6
        for (int kq = 0; kq < D9 / 4; ++kq) {
            float4 hq = tv[kq];
            float4 x0 = r0[kq]; a0 += x0.x*hq.x + x0.y*hq.y + x0.z*hq.z + x0.w*hq.w;
            float4 x1 = r1[kq]; a1 += x1.x*hq.x + x1.y*hq.y + x1.z*hq.z + x1.w*hq.w;
            float4 x2 = r2[kq]; a2 += x2.x*hq.x + x2.y*hq.y + x2.z*hq.z + x2.w*hq.w;
        }
    }
    a0 += b2[j0]; a1 += b2[j1]; a2 += b2[j2];
    {
        float m2 = (l < 16) ? a2 : 0.f;
        float s = a0 + a1 + m2;
        float q = a0*a0 + a1*a1 + m2*m2;
        #pragma unroll
        for (int off = 32; off >= 1; off >>= 1) { s += __shfl_xor(s, off); q += __shfl_xor(q, off); }
        float mu = s * (1.0f / 144.0f);
        float rs = rsqrtf(q * (1.0f / 144.0f) - mu * mu + 1e-5f);
        tout[n * D9 + j0] = siluf_((a0 - mu) * rs * g2[j0] + be2[j0]);
        tout[n * D9 + j1] = siluf_((a1 - mu) * rs * g2[j1] + be2[j1]);
        if (l < 16) tout[n * D9 + j2] = siluf_((a2 - mu) * rs * g2[j2] + be2[j2]);
    }
}

// ---------------- v_gemm: v[n] = WiR @ h[n]  (bf16x3-split MFMA) ----------------
__global__ __launch_bounds__(256) void v_gemm_k(
    const float* __restrict__ h, const u16* __restrict__ Wq,
    float* __restrict__ v)
{
  const int t = threadIdx.x;
  const int w = t >> 6, l = t & 63, lr = l & 15, lg = l >> 4;
  const int nb = blockIdx.x * 16;

  const float* qA = h + (size_t)(nb + lr) * HD + lg*8;
  const u16* bv[8];
  #pragma unroll
  for (int nt = 0; nt < 8; ++nt){
    int n = w*128 + nt*16 + lr;
    bv[nt] = Wq + 131072 + n*128 + lg*8;   // WiR_hi (lo at +65536)
  }

  f32x4 av[8];
  #pragma unroll
  for (int nt = 0; nt < 8; ++nt) av[nt] = (f32x4){0,0,0,0};

  #pragma unroll
  for (int ks = 0; ks < 4; ++ks){
    float4 x0 = *(const float4*)(qA + ks*32);
    float4 x1 = *(const float4*)(qA + ks*32 + 4);
    float xs[8] = {x0.x, x0.y, x0.z, x0.w, x1.x, x1.y, x1.z, x1.w};
    short8 aH, aL;
    #pragma unroll
    for (int j = 0; j < 8; ++j){
      u16 hh = f2bf(xs[j]);
      aH[j] = (short)hh;
      aL[j] = (short)f2bf(xs[j] - bf2f(hh));
    }
    #pragma unroll
    for (int nt = 0; nt < 8; ++nt){
      short8 cH = *(const short8*)(bv[nt] + ks*32);
      short8 cL = *(const short8*)(bv[nt] + 65536 + ks*32);
      av[nt] = __builtin_amdgcn_mfma_f32_16x16x32_bf16(aH, cH, av[nt], 0, 0, 0);
      av[nt] = __builtin_amdgcn_mfma_f32_16x16x32_bf16(aL, cH, av[nt], 0, 0, 0);
      av[nt] = __builtin_amdgcn_mfma_f32_16x16x32_bf16(aH, cL, av[nt], 0, 0, 0);
    }
  }

  #pragma unroll
  for (int nt = 0; nt < 8; ++nt){
    int n = w*128 + nt*16 + lr;
    #pragma unroll
    for (int r = 0; r < 4; ++r){
      size_t node = nb + lg*4 + r;
      v[node*512 + n] = av[nt][r];
    }
  }
}

// ---------------- gather_k: per-node gather, zero atomics ----------------
// Block = 16 nodes x 16 channels. Phase 1: u[nodes] = WiL@h + bi via MFMA -> LDS.
// Phase 2: each 16-lane group loops its node's incident edges (CSR), computing
// z -> LN -> sigmoid -> rotate -> contract, accumulating o in registers.
// One plain 9-store per (node, channel) at the end.
__global__ __launch_bounds__(256) void gather_k(
    const float* __restrict__ h, const u16* __restrict__ Wq,
    const float* __restrict__ bi,
    const float* __restrict__ v, const float* __restrict__ frames,
    const float* __restrict__ tens,
    const float* __restrict__ gi, const float* __restrict__ bei,
    const uint32* __restrict__ start, const u16* __restrict__ srow,
    float* __restrict__ out)
{
  __shared__ float u_lds[16 * 520];   // [node][520] (pad: 520%32=8 spreads banks)
  __shared__ float2 gb_lds[512];      // (gi, bei) pairs

  const int t  = threadIdx.x;
  const int w  = t >> 6, l = t & 63, lr = l & 15, lg = l >> 4;
  const int nb = blockIdx.x * 16;

  // ---- phase 1: u = WiL @ h[nb..nb+15] + bi  (bf16x3 MFMA) ----
  {
    const float* qA = h + (size_t)(nb + lr) * HD + lg*8;
    f32x4 au[8];
    #pragma unroll
    for (int nt = 0; nt < 8; ++nt) au[nt] = (f32x4){0,0,0,0};

    #pragma unroll
    for (int ks = 0; ks < 4; ++ks){
      float4 x0 = *(const float4*)(qA + ks*32);
      float4 x1 = *(const float4*)(qA + ks*32 + 4);
      float xs[8] = {x0.x, x0.y, x0.z, x0.w, x1.x, x1.y, x1.z, x1.w};
      short8 aH, aL;
      #pragma unroll
      for (int j = 0; j < 8; ++j){
        u16 hh = f2bf(xs[j]);
        aH[j] = (short)hh;
        aL[j] = (short)f2bf(xs[j] - bf2f(hh));
      }
      #pragma unroll
      for (int nt = 0; nt < 8; ++nt){
        const u16* bu = Wq + (w*128 + nt*16 + lr)*128 + lg*8 + ks*32;  // WiL_hi
        short8 bH = *(const short8*)bu;
        short8 bL = *(const short8*)(bu + 65536);                      // WiL_lo
        au[nt] = __builtin_amdgcn_mfma_f32_16x16x32_bf16(aH, bH, au[nt], 0, 0, 0);
        au[nt] = __builtin_amdgcn_mfma_f32_16x16x32_bf16(aL, bH, au[nt], 0, 0, 0);
        au[nt] = __builtin_amdgcn_mfma_f32_16x16x32_bf16(aH, bL, au[nt], 0, 0, 0);
      }
    }

    gb_lds[t]       = (float2){gi[t],       bei[t]};
    gb_lds[t + 256] = (float2){gi[t + 256], bei[t + 256]};

    #pragma unroll
    for (int nt = 0; nt < 8; ++nt){
      int n = w*128 + nt*16 + lr;
      float bb = bi[n];
      #pragma unroll
      for (int r = 0; r < 4; ++r)
        u_lds[(lg*4 + r)*520 + n] = au[nt][r] + bb;
    }
  }
  __syncthreads();

  // ---- phase 2: per-node edge loop ----
  const int e3 = t >> 4, c = t & 15;
  const int n  = nb + e3;

  float uu[32];
  #pragma unroll
  for (int k = 0; k < 32; ++k) uu[k] = u_lds[e3*520 + k*16 + c];

  float Rn[9];
  {
    const float* fp = frames + (size_t)n * 9;
    #pragma unroll
    for (int m = 0; m < 9; ++m) Rn[m] = fp[m];
  }
  float TI[9];
  {
    const float* tip = tens + (size_t)n * D9 + c*9;
    #pragma unroll
    for (int m = 0; m < 9; ++m) TI[m] = tip[m];
  }

  float o[9];
  #pragma unroll
  for (int m = 0; m < 9; ++m) o[m] = 0.f;

  const uint32 beg = (n == 0) ? 0u : start[n - 1];   // post-scatter: start[n] = end(n)
  const uint32 end = start[n];

  for (uint32 idx = beg; idx < end; ++idx){
    const int row = (int)srow[idx];

    // z[k] = u[n][k*16+c] + v[row][k*16+c]
    const float* vp = v + (size_t)row * 512 + c;
    float z[32];
    #pragma unroll
    for (int k = 0; k < 32; ++k) z[k] = uu[k] + vp[k*16];

    // LN over 512 (32/lane x 16 lanes)
    float s = 0.f, q = 0.f;
    #pragma unroll
    for (int k = 0; k < 32; ++k){ s += z[k]; q += z[k]*z[k]; }
    #pragma unroll
    for (int off = 1; off < 16; off <<= 1){ s += __shfl_xor(s, off); q += __shfl_xor(q, off); }
    float mu = s * (1.0f/512.0f);
    float rs = rsqrtf(q * (1.0f/512.0f) - mu*mu + 1e-5f);

    // R_rel = Rn^T @ Rj
    const float* Rj = frames + (size_t)row * 9;
    float R[9];
    #pragma unroll
    for (int i = 0; i < 3; ++i)
      #pragma unroll
      for (int j = 0; j < 3; ++j)
        R[i*3+j] = Rn[i]*Rj[j] + Rn[3+i]*Rj[3+j] + Rn[6+i]*Rj[6+j];

    // tj rotate: B = R @ T @ R
    const float* tjp = tens + (size_t)row * D9 + c*9;
    float T[9];
    #pragma unroll
    for (int m = 0; m < 9; ++m) T[m] = tjp[m];
    float A[9], B[9];
    #pragma unroll
    for (int i = 0; i < 3; ++i)
      #pragma unroll
      for (int j = 0; j < 3; ++j)
        A[i*3+j] = R[i*3+0]*T[0+j] + R[i*3+1]*T[3+j] + R[i*3+2]*T[6+j];
    #pragma unroll
    for (int i = 0; i < 3; ++i)
      #pragma unroll
      for (int j = 0; j < 3; ++j)
        B[i*3+j] = A[i*3+0]*R[0+j] + A[i*3+1]*R[3+j] + A[i*3+2]*R[6+j];

    // w + contraction (lane k holds channel-k ti / rotated-tj)
    #pragma unroll
    for (int k = 0; k < 16; ++k){
      float2 gb = gb_lds[k*16 + c];
      float wk = sigmoidf_((z[k] - mu) * rs * gb.x + gb.y);
      #pragma unroll
      for (int m = 0; m < 9; ++m) o[m] += __shfl(TI[m], k, 16) * wk;
    }
    #pragma unroll
    for (int k = 0; k < 16; ++k){
      float2 gb = gb_lds[(16 + k)*16 + c];
      float wk = sigmoidf_((z[16 + k] - mu) * rs * gb.x + gb.y);
      #pragma unroll
      for (int m = 0; m < 9; ++m) o[m] += __shfl(B[m], k, 16) * wk;
    }
  }

  // symmetrize + single write (no atomics)
  float s01 = 0.5f*(o[1]+o[3]), s02 = 0.5f*(o[2]+o[6]), s12 = 0.5f*(o[5]+o[7]);
  float* op = out + (size_t)n * D9 + c*9;
  op[0] = o[0]; op[1] = s01;  op[2] = s02;
  op[3] = s01;  op[4] = o[4]; op[5] = s12;
  op[6] = s02;  op[7] = s12;  op[8] = o[8];
}

extern "C" void kernel_launch(void* const* d_in, const int* in_sizes, int n_in,
                              void* d_out, int out_size, void* d_ws, size_t ws_size,
                              hipStream_t stream) {
    const float* h      = (const float*)d_in[1];
    const float* frames = (const float*)d_in[2];
    const int*   ei     = (const int*)d_in[3];
    const float* W1  = (const float*)d_in[5];
    const float* b1  = (const float*)d_in[6];
    const float* g1  = (const float*)d_in[7];
    const float* be1 = (const float*)d_in[8];
    const float* W2  = (const float*)d_in[9];
    const float* b2  = (const float*)d_in[10];
    const float* g2  = (const float*)d_in[11];
    const float* be2 = (const float*)d_in[12];
    const float* Wi  = (const float*)d_in[13];
    const float* bi  = (const float*)d_in[14];
    const float* gi  = (const float*)d_in[15];
    const float* bei = (const float*)d_in[16];

    float* out = (float*)d_out;

    // ws layout (~80 MB; round 6 proved ws >= 140.68 MB):
    float*  v     = (float*)d_ws;                          // [N,512] f32 : 61,440,000 B
    float*  tens  = (float*)((char*)d_ws + 61440000);      // [N,144] f32 : 17,280,000 B
    u16*    Wq    = (u16*)  ((char*)d_ws + 78720000);      // 4x[512x128] bf16 : 524,288 B
    uint32* start = (uint32*)((char*)d_ws + 79244288);     // [N+64] u32 : 120,256 B
    u16*    srow  = (u16*)  ((char*)d_ws + 79364544);      // [E] u16 : 600,000 B

    hipMemsetAsync(start, 0, (NN + 1) * sizeof(uint32), stream);

    cvt_wq_k<<<256, 256, 0, stream>>>(Wi, Wq);
    tensor_init_k<<<NN/4, 256, 0, stream>>>(h, W1, b1, g1, be1, W2, b2, g2, be2, tens);
    v_gemm_k<<<NN/16, 256, 0, stream>>>(h, Wq, v);
    hist_k<<<(EE + 255)/256, 256, 0, stream>>>(ei, start);
    scan_k<<<1, 1024, 0, stream>>>(start);
    scatter_k<<<(EE + 255)/256, 256, 0, stream>>>(ei, start, srow);
    gather_k<<<NN/16, 256, 0, stream>>>(h, Wq, bi, v, frames, tens, gi, bei, start, srow, out);
}

// Round 8
// 1272.152 us; speedup vs baseline: 2.5168x; 1.0181x over previous
//
#include <hip/hip_runtime.h>

#define NN 30000
#define EE 300000
#define HD 128
#define D9 144

typedef unsigned int uint32;
typedef unsigned short u16;
typedef __attribute__((ext_vector_type(8))) short short8;
typedef __attribute__((ext_vector_type(4))) float f32x4;

__device__ __forceinline__ float sigmoidf_(float x){ return 1.0f/(1.0f+__expf(-x)); }
__device__ __forceinline__ float siluf_(float x){ return x/(1.0f+__expf(-x)); }
__device__ __forceinline__ u16 f2bf(float f){
  uint32 u = __float_as_uint(f);
  return (u16)((u + 0x7fffu + ((u>>16)&1u)) >> 16);   // RNE
}
__device__ __forceinline__ float bf2f(u16 b){ return __uint_as_float(((uint32)b)<<16); }

// ---------------- Wi -> [WiL_hi | WiL_lo | WiR_hi | WiR_lo], each [512x128] ----------------
__global__ __launch_bounds__(256) void cvt_wq_k(const float* __restrict__ Wi, u16* __restrict__ Wq){
  int i = blockIdx.x*256 + threadIdx.x;
  if (i < 512*128){
    int n = i >> 7, k = i & 127;
    float xl = Wi[n*256 + k];
    float xr = Wi[n*256 + 128 + k];
    u16 lh = f2bf(xl);
    Wq[i]          = lh;
    Wq[65536 + i]  = f2bf(xl - bf2f(lh));
    u16 rh = f2bf(xr);
    Wq[131072 + i] = rh;
    Wq[196608 + i] = f2bf(xr - bf2f(rh));
  }
}

// ---------------- CSR build: hist -> scan -> scatter ----------------
__global__ __launch_bounds__(256) void hist_k(const int* __restrict__ ei, uint32* __restrict__ start){
  int e = blockIdx.x*256 + threadIdx.x;
  if (e < EE){
    int col = ei[EE + e];
    col = col < 0 ? 0 : (col >= NN ? NN-1 : col);
    atomicAdd(&start[col], 1u);
  }
}

__global__ __launch_bounds__(1024) void scan_k(uint32* __restrict__ start){
  __shared__ uint32 part[1024];
  const int t = threadIdx.x;
  const int base = t * 30;
  uint32 loc[30];
  uint32 s = 0;
  #pragma unroll
  for (int i = 0; i < 30; ++i){
    int idx = base + i;
    uint32 cv = (idx < NN) ? start[idx] : 0u;
    loc[i] = s;
    s += cv;
  }
  part[t] = s;
  __syncthreads();
  for (int off = 1; off < 1024; off <<= 1){
    uint32 add = (t >= off) ? part[t - off] : 0u;
    __syncthreads();
    part[t] += add;
    __syncthreads();
  }
  uint32 pre = (t == 0) ? 0u : part[t - 1];
  #pragma unroll
  for (int i = 0; i < 30; ++i){
    int idx = base + i;
    if (idx < NN) start[idx] = pre + loc[i];
  }
}

__global__ __launch_bounds__(256) void scatter_k(const int* __restrict__ ei,
                                                 uint32* __restrict__ start,
                                                 u16* __restrict__ srow){
  int e = blockIdx.x*256 + threadIdx.x;
  if (e < EE){
    int row = ei[e];
    row = row < 0 ? 0 : (row >= NN ? NN-1 : row);
    int col = ei[EE + e];
    col = col < 0 ? 0 : (col >= NN ? NN-1 : col);
    uint32 pos = atomicAdd(&start[col], 1u);   // start becomes end(col)
    srow[pos] = (u16)row;
  }
}

// ---------------- Kernel A: tensor_init (all-f32, verified) ----------------
__global__ __launch_bounds__(256) void tensor_init_k(
    const float* __restrict__ h,
    const float* __restrict__ W1, const float* __restrict__ b1,
    const float* __restrict__ g1, const float* __restrict__ be1,
    const float* __restrict__ W2, const float* __restrict__ b2,
    const float* __restrict__ g2, const float* __restrict__ be2,
    float* __restrict__ tout)
{
    __shared__ float h_s[4][128];
    __shared__ float t_s[4][160];
    const int w = threadIdx.x >> 6;
    const int l = threadIdx.x & 63;
    const int n = blockIdx.x * 4 + w;

    h_s[w][l]      = h[n * HD + l];
    h_s[w][l + 64] = h[n * HD + l + 64];
    __syncthreads();

    const int j0 = l, j1 = 64 + l, j2 = 128 + (l & 15);

    float a0 = 0.f, a1 = 0.f, a2 = 0.f;
    {
        const float4* r0 = (const float4*)(W1 + j0 * HD);
        const float4* r1 = (const float4*)(W1 + j1 * HD);
        const float4* r2 = (const float4*)(W1 + j2 * HD);
        const float4* hv = (const float4*)(&h_s[w][0]);
        #pragma unroll 8
        for (int kq = 0; kq < HD / 4; ++kq) {
            float4 hq = hv[kq];
            float4 x0 = r0[kq]; a0 += x0.x*hq.x + x0.y*hq.y + x0.z*hq.z + x0.w*hq.w;
            float4 x1 = r1[kq]; a1 += x1.x*hq.x + x1.y*hq.y + x1.z*hq.z + x1.w*hq.w;
            float4 x2 = r2[kq]; a2 += x2.x*hq.x + x2.y*hq.y + x2.z*hq.z + x2.w*hq.w;
        }
    }
    a0 += b1[j0]; a1 += b1[j1]; a2 += b1[j2];
    {
        float m2 = (l < 16) ? a2 : 0.f;
        float s = a0 + a1 + m2;
        float q = a0*a0 + a1*a1 + m2*m2;
        #pragma unroll
        for (int off = 32; off >= 1; off >>= 1) { s += __shfl_xor(s, off); q += __shfl_xor(q, off); }
        float mu = s * (1.0f / 144.0f);
        float rs = rsqrtf(q * (1.0f / 144.0f) - mu * mu + 1e-5f);
        t_s[w][j0] = siluf_((a0 - mu) * rs * g1[j0] + be1[j0]);
        t_s[w][j1] = siluf_((a1 - mu) * rs * g1[j1] + be1[j1]);
        if (l < 16) t_s[w][j2] = siluf_((a2 - mu) * rs * g1[j2] + be1[j2]);
    }
    __syncthreads();

    a0 = a1 = a2 = 0.f;
    {
        const float4* r0 = (const float4*)(W2 + j0 * D9);
        const float4* r1 = (const float4*)(W2 + j1 * D9);
        const float4* r2 = (const float4*)(W2 + j2 * D9);
        const float4* tv = (const float4*)(&t_s[w][0]);
        #pragma unroll 6
        for (int kq = 0; kq < D9 / 4; ++kq) {
            float4 hq = tv[kq];
            float4 x0 = r0[kq]; a0 += x0.x*hq.x + x0.y*hq.y + x0.z*hq.z + x0.w*hq.w;
            float4 x1 = r1[kq]; a1 += x1.x*hq.x + x1.y*hq.y + x1.z*hq.z + x1.w*hq.w;
            float4 x2 = r2[kq]; a2 += x2.x*hq.x + x2.y*hq.y + x2.z*hq.z + x2.w*hq.w;
        }
    }
    a0 += b2[j0]; a1 += b2[j1]; a2 += b2[j2];
    {
        float m2 = (l < 16) ? a2 : 0.f;
        float s = a0 + a1 + m2;
        float q = a0*a0 + a1*a1 + m2*m2;
        #pragma unroll
        for (int off = 32; off >= 1; off >>= 1) { s += __shfl_xor(s, off); q += __shfl_xor(q, off); }
        float mu = s * (1.0f / 144.0f);
        float rs = rsqrtf(q * (1.0f / 144.0f) - mu * mu + 1e-5f);
        tout[n * D9 + j0] = siluf_((a0 - mu) * rs * g2[j0] + be2[j0]);
        tout[n * D9 + j1] = siluf_((a1 - mu) * rs * g2[j1] + be2[j1]);
        if (l < 16) tout[n * D9 + j2] = siluf_((a2 - mu) * rs * g2[j2] + be2[j2]);
    }
}

// ---------------- node_gemm: u[n]=WiL@h[n]+bi (f32), v[n]=WiR@h[n] (bf16) ----------------
__global__ __launch_bounds__(256) void node_gemm_k(
    const float* __restrict__ h, const u16* __restrict__ Wq,
    const float* __restrict__ bi,
    float* __restrict__ u, u16* __restrict__ v16)
{
  const int t = threadIdx.x;
  const int w = t >> 6, l = t & 63, lr = l & 15, lg = l >> 4;
  const int nb = blockIdx.x * 16;

  const float* qA = h + (size_t)(nb + lr) * HD + lg*8;
  f32x4 au[8], av[8];
  #pragma unroll
  for (int nt = 0; nt < 8; ++nt){ au[nt] = (f32x4){0,0,0,0}; av[nt] = (f32x4){0,0,0,0}; }

  #pragma unroll
  for (int ks = 0; ks < 4; ++ks){
    float4 x0 = *(const float4*)(qA + ks*32);
    float4 x1 = *(const float4*)(qA + ks*32 + 4);
    float xs[8] = {x0.x, x0.y, x0.z, x0.w, x1.x, x1.y, x1.z, x1.w};
    short8 aH, aL;
    #pragma unroll
    for (int j = 0; j < 8; ++j){
      u16 hh = f2bf(xs[j]);
      aH[j] = (short)hh;
      aL[j] = (short)f2bf(xs[j] - bf2f(hh));
    }
    #pragma unroll
    for (int nt = 0; nt < 8; ++nt){
      const u16* bu = Wq + (w*128 + nt*16 + lr)*128 + lg*8 + ks*32;
      short8 bH = *(const short8*)bu;
      short8 bL = *(const short8*)(bu + 65536);
      au[nt] = __builtin_amdgcn_mfma_f32_16x16x32_bf16(aH, bH, au[nt], 0, 0, 0);
      au[nt] = __builtin_amdgcn_mfma_f32_16x16x32_bf16(aL, bH, au[nt], 0, 0, 0);
      au[nt] = __builtin_amdgcn_mfma_f32_16x16x32_bf16(aH, bL, au[nt], 0, 0, 0);
      const u16* bv = bu + 131072;
      short8 cH = *(const short8*)bv;
      short8 cL = *(const short8*)(bv + 65536);
      av[nt] = __builtin_amdgcn_mfma_f32_16x16x32_bf16(aH, cH, av[nt], 0, 0, 0);
      av[nt] = __builtin_amdgcn_mfma_f32_16x16x32_bf16(aL, cH, av[nt], 0, 0, 0);
      av[nt] = __builtin_amdgcn_mfma_f32_16x16x32_bf16(aH, cL, av[nt], 0, 0, 0);
    }
  }

  #pragma unroll
  for (int nt = 0; nt < 8; ++nt){
    int n = w*128 + nt*16 + lr;
    float bb = bi[n];
    #pragma unroll
    for (int r = 0; r < 4; ++r){
      size_t node = nb + lg*4 + r;
      u[node*512 + n]   = au[nt][r] + bb;
      v16[node*512 + n] = f2bf(av[nt][r]);
    }
  }
}

// ---------------- gather2: 4 nodes x 4 slots x 16 ch per block ----------------
// wave = one node (4 slot-groups). Slots process edges beg+slot, +4, ...
// Final o-reduce over slots = shfl_xor(16) + shfl_xor(32). One store per (n,c).
__global__ __launch_bounds__(256) void gather2_k(
    const float* __restrict__ u, const u16* __restrict__ v16,
    const float* __restrict__ frames, const float* __restrict__ tens,
    const float* __restrict__ gi, const float* __restrict__ bei,
    const uint32* __restrict__ start, const u16* __restrict__ srow,
    float* __restrict__ out)
{
  __shared__ float u_lds[4 * 520];
  __shared__ float2 gb_lds[512];

  const int t  = threadIdx.x;
  const int nl = t >> 6;          // node-local 0..3 (= wave)
  const int sl = (t >> 4) & 3;    // slot 0..3
  const int c  = t & 15;          // channel
  const int nb = blockIdx.x * 4;
  const int n  = nb + nl;

  // stage u rows + (gi,bei)
  {
    const int off = (t & 63) * 8;
    const float4* src = (const float4*)(u + (size_t)(nb + nl) * 512 + off);
    float4 a = src[0], b = src[1];
    *(float4*)&u_lds[nl*520 + off]     = a;
    *(float4*)&u_lds[nl*520 + off + 4] = b;
    gb_lds[t]       = (float2){gi[t],       bei[t]};
    gb_lds[t + 256] = (float2){gi[t + 256], bei[t + 256]};
  }
  __syncthreads();

  float Rn[9];
  {
    const float* fp = frames + (size_t)n * 9;
    #pragma unroll
    for (int m = 0; m < 9; ++m) Rn[m] = fp[m];
  }
  float TI[9];
  {
    const float* tip = tens + (size_t)n * D9 + c*9;
    #pragma unroll
    for (int m = 0; m < 9; ++m) TI[m] = tip[m];
  }

  float o[9];
  #pragma unroll
  for (int m = 0; m < 9; ++m) o[m] = 0.f;

  const uint32 beg = (n == 0) ? 0u : start[n - 1];
  const uint32 end = start[n];

  for (uint32 idx = beg + sl; idx < end; idx += 4){
    const int row = (int)srow[idx];

    // z[k] = u[n][k*16+c] + v[row][k*16+c]
    const u16* vp = v16 + (size_t)row * 512 + c;
    float z[32];
    #pragma unroll
    for (int k = 0; k < 32; ++k)
      z[k] = u_lds[nl*520 + k*16 + c] + bf2f(vp[k*16]);

    // LN over 512 (32/lane x 16 lanes; xor<16 stays within slot-group)
    float s = 0.f, q = 0.f;
    #pragma unroll
    for (int k = 0; k < 32; ++k){ s += z[k]; q += z[k]*z[k]; }
    #pragma unroll
    for (int off = 1; off < 16; off <<= 1){ s += __shfl_xor(s, off); q += __shfl_xor(q, off); }
    float mu = s * (1.0f/512.0f);
    float rs = rsqrtf(q * (1.0f/512.0f) - mu*mu + 1e-5f);

    // R_rel = Rn^T @ Rj
    const float* Rj = frames + (size_t)row * 9;
    float R[9];
    #pragma unroll
    for (int i = 0; i < 3; ++i)
      #pragma unroll
      for (int j = 0; j < 3; ++j)
        R[i*3+j] = Rn[i]*Rj[j] + Rn[3+i]*Rj[3+j] + Rn[6+i]*Rj[6+j];

    // B = R @ T @ R
    const float* tjp = tens + (size_t)row * D9 + c*9;
    float T[9];
    #pragma unroll
    for (int m = 0; m < 9; ++m) T[m] = tjp[m];
    float A[9], B[9];
    #pragma unroll
    for (int i = 0; i < 3; ++i)
      #pragma unroll
      for (int j = 0; j < 3; ++j)
        A[i*3+j] = R[i*3+0]*T[0+j] + R[i*3+1]*T[3+j] + R[i*3+2]*T[6+j];
    #pragma unroll
    for (int i = 0; i < 3; ++i)
      #pragma unroll
      for (int j = 0; j < 3; ++j)
        B[i*3+j] = A[i*3+0]*R[0+j] + A[i*3+1]*R[3+j] + A[i*3+2]*R[6+j];

    // w + contraction
    #pragma unroll
    for (int k = 0; k < 16; ++k){
      float2 gb = gb_lds[k*16 + c];
      float wk = sigmoidf_((z[k] - mu) * rs * gb.x + gb.y);
      #pragma unroll
      for (int m = 0; m < 9; ++m) o[m] += __shfl(TI[m], k, 16) * wk;
    }
    #pragma unroll
    for (int k = 0; k < 16; ++k){
      float2 gb = gb_lds[(16 + k)*16 + c];
      float wk = sigmoidf_((z[16 + k] - mu) * rs * gb.x + gb.y);
      #pragma unroll
      for (int m = 0; m < 9; ++m) o[m] += __shfl(B[m], k, 16) * wk;
    }
  }

  // reduce over slots (lanes 16 and 32 apart)
  #pragma unroll
  for (int m = 0; m < 9; ++m){
    o[m] += __shfl_xor(o[m], 16);
    o[m] += __shfl_xor(o[m], 32);
  }

  if (sl == 0){
    float s01 = 0.5f*(o[1]+o[3]), s02 = 0.5f*(o[2]+o[6]), s12 = 0.5f*(o[5]+o[7]);
    float* op = out + (size_t)n * D9 + c*9;
    op[0] = o[0]; op[1] = s01;  op[2] = s02;
    op[3] = s01;  op[4] = o[4]; op[5] = s12;
    op[6] = s02;  op[7] = s12;  op[8] = o[8];
  }
}

extern "C" void kernel_launch(void* const* d_in, const int* in_sizes, int n_in,
                              void* d_out, int out_size, void* d_ws, size_t ws_size,
                              hipStream_t stream) {
    const float* h      = (const float*)d_in[1];
    const float* frames = (const float*)d_in[2];
    const int*   ei     = (const int*)d_in[3];
    const float* W1  = (const float*)d_in[5];
    const float* b1  = (const float*)d_in[6];
    const float* g1  = (const float*)d_in[7];
    const float* be1 = (const float*)d_in[8];
    const float* W2  = (const float*)d_in[9];
    const float* b2  = (const float*)d_in[10];
    const float* g2  = (const float*)d_in[11];
    const float* be2 = (const float*)d_in[12];
    const float* Wi  = (const float*)d_in[13];
    const float* bi  = (const float*)d_in[14];
    const float* gi  = (const float*)d_in[15];
    const float* bei = (const float*)d_in[16];

    float* out = (float*)d_out;

    // ws layout (~110.7 MB; proven ws >= 140.68 MB in round 6):
    float*  u     = (float*)d_ws;                           // [N,512] f32 : 61,440,000
    u16*    v16   = (u16*)  ((char*)d_ws + 61440000);       // [N,512] bf16: 30,720,000
    float*  tens  = (float*)((char*)d_ws + 92160000);       // [N,144] f32 : 17,280,000
    u16*    Wq    = (u16*)  ((char*)d_ws + 109440000);      // 4x[512x128] bf16 : 524,288
    uint32* start = (uint32*)((char*)d_ws + 109964288);     // [N] u32 : 120,000
    u16*    srow  = (u16*)  ((char*)d_ws + 110084288);      // [E] u16 : 600,000

    hipMemsetAsync(start, 0, NN * sizeof(uint32), stream);

    cvt_wq_k<<<256, 256, 0, stream>>>(Wi, Wq);
    tensor_init_k<<<NN/4, 256, 0, stream>>>(h, W1, b1, g1, be1, W2, b2, g2, be2, tens);
    node_gemm_k<<<NN/16, 256, 0, stream>>>(h, Wq, bi, u, v16);
    hist_k<<<(EE + 255)/256, 256, 0, stream>>>(ei, start);
    scan_k<<<1, 1024, 0, stream>>>(start);
    scatter_k<<<(EE + 255)/256, 256, 0, stream>>>(ei, start, srow);
    gather2_k<<<NN/4, 256, 0, stream>>>(u, v16, frames, tens, gi, bei, start, srow, out);
}

// Round 9
// 786.485 us; speedup vs baseline: 4.0710x; 1.6175x over previous
//
#include <hip/hip_runtime.h>

#define NN 30000
#define EE 300000
#define HD 128
#define D9 144

typedef unsigned int uint32;
typedef unsigned short u16;
typedef __attribute__((ext_vector_type(8))) short short8;
typedef __attribute__((ext_vector_type(4))) float f32x4;
typedef __attribute__((ext_vector_type(4))) uint32 u32x4;

__device__ __forceinline__ float sigmoidf_(float x){ return 1.0f/(1.0f+__expf(-x)); }
__device__ __forceinline__ float siluf_(float x){ return x/(1.0f+__expf(-x)); }
__device__ __forceinline__ u16 f2bf(float f){
  uint32 u = __float_as_uint(f);
  return (u16)((u + 0x7fffu + ((u>>16)&1u)) >> 16);   // RNE
}
__device__ __forceinline__ float bf2f(u16 b){ return __uint_as_float(((uint32)b)<<16); }
__device__ __forceinline__ float bflo(uint32 u){ return __uint_as_float(u<<16); }
__device__ __forceinline__ float bfhi(uint32 u){ return __uint_as_float(u & 0xffff0000u); }
__device__ __forceinline__ uint32 pk2(float a, float b){ return (uint32)f2bf(a) | ((uint32)f2bf(b)<<16); }

// ---------------- Wi -> [WiL_hi | WiL_lo | WiR_hi | WiR_lo], each [512x128] ----------------
__global__ __launch_bounds__(256) void cvt_wq_k(const float* __restrict__ Wi, u16* __restrict__ Wq){
  int i = blockIdx.x*256 + threadIdx.x;
  if (i < 512*128){
    int n = i >> 7, k = i & 127;
    float xl = Wi[n*256 + k];
    float xr = Wi[n*256 + 128 + k];
    u16 lh = f2bf(xl);
    Wq[i]          = lh;
    Wq[65536 + i]  = f2bf(xl - bf2f(lh));
    u16 rh = f2bf(xr);
    Wq[131072 + i] = rh;
    Wq[196608 + i] = f2bf(xr - bf2f(rh));
  }
}

// ---------------- W1 [144x128] -> hi/lo ----------------
__global__ __launch_bounds__(256) void cvt_w1s_k(const float* __restrict__ W1, u16* __restrict__ W1s){
  int i = blockIdx.x*256 + threadIdx.x;
  if (i < 144*128){
    float x = W1[i];
    u16 hh = f2bf(x);
    W1s[i] = hh;
    W1s[18432 + i] = f2bf(x - bf2f(hh));
  }
}
// ---------------- W2 [144x144] -> hi/lo padded [144x160] ----------------
__global__ __launch_bounds__(256) void cvt_w2s_k(const float* __restrict__ W2, u16* __restrict__ W2s){
  int i = blockIdx.x*256 + threadIdx.x;
  if (i < 144*160){
    int r = i / 160, k = i - r*160;
    float x = (k < 144) ? W2[r*144 + k] : 0.f;
    u16 hh = f2bf(x);
    W2s[i] = hh;
    W2s[23040 + i] = f2bf(x - bf2f(hh));
  }
}

// ---------------- CSR build: hist -> scan -> scatter ----------------
__global__ __launch_bounds__(256) void hist_k(const int* __restrict__ ei, uint32* __restrict__ start){
  int e = blockIdx.x*256 + threadIdx.x;
  if (e < EE){
    int col = ei[EE + e];
    col = col < 0 ? 0 : (col >= NN ? NN-1 : col);
    atomicAdd(&start[col], 1u);
  }
}

__global__ __launch_bounds__(1024) void scan_k(uint32* __restrict__ start){
  __shared__ uint32 part[1024];
  const int t = threadIdx.x;
  const int base = t * 30;
  uint32 loc[30];
  uint32 s = 0;
  #pragma unroll
  for (int i = 0; i < 30; ++i){
    int idx = base + i;
    uint32 cv = (idx < NN) ? start[idx] : 0u;
    loc[i] = s;
    s += cv;
  }
  part[t] = s;
  __syncthreads();
  for (int off = 1; off < 1024; off <<= 1){
    uint32 add = (t >= off) ? part[t - off] : 0u;
    __syncthreads();
    part[t] += add;
    __syncthreads();
  }
  uint32 pre = (t == 0) ? 0u : part[t - 1];
  #pragma unroll
  for (int i = 0; i < 30; ++i){
    int idx = base + i;
    if (idx < NN) start[idx] = pre + loc[i];
  }
}

__global__ __launch_bounds__(256) void scatter_k(const int* __restrict__ ei,
                                                 uint32* __restrict__ start,
                                                 u16* __restrict__ srow){
  int e = blockIdx.x*256 + threadIdx.x;
  if (e < EE){
    int row = ei[e];
    row = row < 0 ? 0 : (row >= NN ? NN-1 : row);
    int col = ei[EE + e];
    col = col < 0 ? 0 : (col >= NN ? NN-1 : col);
    uint32 pos = atomicAdd(&start[col], 1u);   // start becomes end(col)
    srow[pos] = (u16)row;
  }
}

// ---------------- tensor_init2: MFMA bf16x3, writes tens_t[n][m*16+c] ----------------
// 16 nodes/block, 4 waves. Wave w owns n-tiles {2w, 2w+1} (+ tile 8 for w==0).
__global__ __launch_bounds__(256) void tensor_init2_k(
    const float* __restrict__ h,
    const u16* __restrict__ W1s, const u16* __restrict__ W2s,
    const float* __restrict__ b1, const float* __restrict__ g1, const float* __restrict__ be1,
    const float* __restrict__ b2, const float* __restrict__ g2, const float* __restrict__ be2,
    float* __restrict__ tens_t)
{
  __shared__ float t1s[16 * 164];   // layer-1 out, padded K to 160 (cols 144..159 = 0)
  __shared__ float pool[160];       // partials [4w][16n][2] -> mu[16]+rs[16]

  const int t = threadIdx.x;
  const int w = t >> 6, l = t & 63, lr = l & 15, lg = l >> 4;
  const int nb = blockIdx.x * 16;
  const int ntile = (w == 0) ? 3 : 2;
  int tiles[3]; tiles[0] = 2*w; tiles[1] = 2*w + 1; tiles[2] = 8;

  // ================= layer 1: z1[16 x 144] = h @ W1^T (K=128) =================
  f32x4 acc[3];
  #pragma unroll
  for (int ti = 0; ti < 3; ++ti) acc[ti] = (f32x4){0,0,0,0};
  {
    const float* qA = h + (size_t)(nb + lr) * HD + lg*8;
    #pragma unroll
    for (int ks = 0; ks < 4; ++ks){
      float4 x0 = *(const float4*)(qA + ks*32);
      float4 x1 = *(const float4*)(qA + ks*32 + 4);
      float xs[8] = {x0.x, x0.y, x0.z, x0.w, x1.x, x1.y, x1.z, x1.w};
      short8 aH, aL;
      #pragma unroll
      for (int j = 0; j < 8; ++j){
        u16 hh = f2bf(xs[j]);
        aH[j] = (short)hh;
        aL[j] = (short)f2bf(xs[j] - bf2f(hh));
      }
      for (int ti = 0; ti < ntile; ++ti){
        const u16* b = W1s + (tiles[ti]*16 + lr)*128 + lg*8 + ks*32;
        short8 bH = *(const short8*)b;
        short8 bL = *(const short8*)(b + 18432);
        acc[ti] = __builtin_amdgcn_mfma_f32_16x16x32_bf16(aH, bH, acc[ti], 0, 0, 0);
        acc[ti] = __builtin_amdgcn_mfma_f32_16x16x32_bf16(aL, bH, acc[ti], 0, 0, 0);
        acc[ti] = __builtin_amdgcn_mfma_f32_16x16x32_bf16(aH, bL, acc[ti], 0, 0, 0);
      }
    }
  }
  // bias + LN(144) + SiLU -> t1s
  for (int ti = 0; ti < ntile; ++ti){
    float bb = b1[tiles[ti]*16 + lr];
    #pragma unroll
    for (int r = 0; r < 4; ++r) acc[ti][r] += bb;
  }
  {
    float ps[4], pq[4];
    #pragma unroll
    for (int r = 0; r < 4; ++r){
      float s = 0.f, q = 0.f;
      for (int ti = 0; ti < ntile; ++ti){ s += acc[ti][r]; q += acc[ti][r]*acc[ti][r]; }
      ps[r] = s; pq[r] = q;
    }
    #pragma unroll
    for (int off = 1; off < 16; off <<= 1)
      #pragma unroll
      for (int r = 0; r < 4; ++r){ ps[r] += __shfl_xor(ps[r], off); pq[r] += __shfl_xor(pq[r], off); }
    if (lr == 0){
      #pragma unroll
      for (int r = 0; r < 4; ++r){
        pool[w*32 + (lg*4 + r)*2 + 0] = ps[r];
        pool[w*32 + (lg*4 + r)*2 + 1] = pq[r];
      }
    }
  }
  __syncthreads();
  if (t < 16){
    float s = pool[t*2] + pool[32 + t*2] + pool[64 + t*2] + pool[96 + t*2];
    float q = pool[t*2+1] + pool[32 + t*2+1] + pool[64 + t*2+1] + pool[96 + t*2+1];
    float mu = s * (1.0f/144.0f);
    pool[128 + t] = mu;
    pool[144 + t] = rsqrtf(q * (1.0f/144.0f) - mu*mu + 1e-5f);
  }
  __syncthreads();
  for (int ti = 0; ti < ntile; ++ti){
    int col = tiles[ti]*16 + lr;
    float gg = g1[col], bb = be1[col];
    #pragma unroll
    for (int r = 0; r < 4; ++r){
      int node = lg*4 + r;
      float mu = pool[128 + node], rs = pool[144 + node];
      t1s[node*164 + col] = siluf_((acc[ti][r] - mu) * rs * gg + bb);
    }
  }
  t1s[(t >> 4)*164 + 144 + (t & 15)] = 0.f;   // zero pad cols 144..159
  __syncthreads();

  // ================= layer 2: z2[16 x 144] = t1 @ W2^T (K=160 padded) =================
  #pragma unroll
  for (int ti = 0; ti < 3; ++ti) acc[ti] = (f32x4){0,0,0,0};
  #pragma unroll
  for (int ks = 0; ks < 5; ++ks){
    float4 x0 = *(const float4*)&t1s[lr*164 + lg*8 + ks*32];
    float4 x1 = *(const float4*)&t1s[lr*164 + lg*8 + ks*32 + 4];
    float xs[8] = {x0.x, x0.y, x0.z, x0.w, x1.x, x1.y, x1.z, x1.w};
    short8 aH, aL;
    #pragma unroll
    for (int j = 0; j < 8; ++j){
      u16 hh = f2bf(xs[j]);
      aH[j] = (short)hh;
      aL[j] = (short)f2bf(xs[j] - bf2f(hh));
    }
    for (int ti = 0; ti < ntile; ++ti){
      const u16* b = W2s + (tiles[ti]*16 + lr)*160 + lg*8 + ks*32;
      short8 bH = *(const short8*)b;
      short8 bL = *(const short8*)(b + 23040);
      acc[ti] = __builtin_amdgcn_mfma_f32_16x16x32_bf16(aH, bH, acc[ti], 0, 0, 0);
      acc[ti] = __builtin_amdgcn_mfma_f32_16x16x32_bf16(aL, bH, acc[ti], 0, 0, 0);
      acc[ti] = __builtin_amdgcn_mfma_f32_16x16x32_bf16(aH, bL, acc[ti], 0, 0, 0);
    }
  }
  for (int ti = 0; ti < ntile; ++ti){
    float bb = b2[tiles[ti]*16 + lr];
    #pragma unroll
    for (int r = 0; r < 4; ++r) acc[ti][r] += bb;
  }
  __syncthreads();   // pool reuse
  {
    float ps[4], pq[4];
    #pragma unroll
    for (int r = 0; r < 4; ++r){
      float s = 0.f, q = 0.f;
      for (int ti = 0; ti < ntile; ++ti){ s += acc[ti][r]; q += acc[ti][r]*acc[ti][r]; }
      ps[r] = s; pq[r] = q;
    }
    #pragma unroll
    for (int off = 1; off < 16; off <<= 1)
      #pragma unroll
      for (int r = 0; r < 4; ++r){ ps[r] += __shfl_xor(ps[r], off); pq[r] += __shfl_xor(pq[r], off); }
    if (lr == 0){
      #pragma unroll
      for (int r = 0; r < 4; ++r){
        pool[w*32 + (lg*4 + r)*2 + 0] = ps[r];
        pool[w*32 + (lg*4 + r)*2 + 1] = pq[r];
      }
    }
  }
  __syncthreads();
  if (t < 16){
    float s = pool[t*2] + pool[32 + t*2] + pool[64 + t*2] + pool[96 + t*2];
    float q = pool[t*2+1] + pool[32 + t*2+1] + pool[64 + t*2+1] + pool[96 + t*2+1];
    float mu = s * (1.0f/144.0f);
    pool[128 + t] = mu;
    pool[144 + t] = rsqrtf(q * (1.0f/144.0f) - mu*mu + 1e-5f);
  }
  __syncthreads();
  for (int ti = 0; ti < ntile; ++ti){
    int col = tiles[ti]*16 + lr;
    float gg = g2[col], bb = be2[col];
    int c = col / 9, m = col - c*9;
    #pragma unroll
    for (int r = 0; r < 4; ++r){
      int node = lg*4 + r;
      float mu = pool[128 + node], rs = pool[144 + node];
      float val = siluf_((acc[ti][r] - mu) * rs * gg + bb);
      tens_t[(size_t)(nb + node)*144 + m*16 + c] = val;
    }
  }
}

// ---------------- node_gemm: u_t[n][c*32+k] f32, v16_t[n][c*32+k] bf16 ----------------
__global__ __launch_bounds__(256) void node_gemm_k(
    const float* __restrict__ h, const u16* __restrict__ Wq,
    const float* __restrict__ bi,
    float* __restrict__ u_t, u16* __restrict__ v16_t)
{
  const int t = threadIdx.x;
  const int w = t >> 6, l = t & 63, lr = l & 15, lg = l >> 4;
  const int nb = blockIdx.x * 16;

  const float* qA = h + (size_t)(nb + lr) * HD + lg*8;
  f32x4 au[8], av[8];
  #pragma unroll
  for (int nt = 0; nt < 8; ++nt){ au[nt] = (f32x4){0,0,0,0}; av[nt] = (f32x4){0,0,0,0}; }

  #pragma unroll
  for (int ks = 0; ks < 4; ++ks){
    float4 x0 = *(const float4*)(qA + ks*32);
    float4 x1 = *(const float4*)(qA + ks*32 + 4);
    float xs[8] = {x0.x, x0.y, x0.z, x0.w, x1.x, x1.y, x1.z, x1.w};
    short8 aH, aL;
    #pragma unroll
    for (int j = 0; j < 8; ++j){
      u16 hh = f2bf(xs[j]);
      aH[j] = (short)hh;
      aL[j] = (short)f2bf(xs[j] - bf2f(hh));
    }
    #pragma unroll
    for (int nt = 0; nt < 8; ++nt){
      const u16* bu = Wq + (w*128 + nt*16 + lr)*128 + lg*8 + ks*32;
      short8 bH = *(const short8*)bu;
      short8 bL = *(const short8*)(bu + 65536);
      au[nt] = __builtin_amdgcn_mfma_f32_16x16x32_bf16(aH, bH, au[nt], 0, 0, 0);
      au[nt] = __builtin_amdgcn_mfma_f32_16x16x32_bf16(aL, bH, au[nt], 0, 0, 0);
      au[nt] = __builtin_amdgcn_mfma_f32_16x16x32_bf16(aH, bL, au[nt], 0, 0, 0);
      const u16* bv = bu + 131072;
      short8 cH = *(const short8*)bv;
      short8 cL = *(const short8*)(bv + 65536);
      av[nt] = __builtin_amdgcn_mfma_f32_16x16x32_bf16(aH, cH, av[nt], 0, 0, 0);
      av[nt] = __builtin_amdgcn_mfma_f32_16x16x32_bf16(aL, cH, av[nt], 0, 0, 0);
      av[nt] = __builtin_amdgcn_mfma_f32_16x16x32_bf16(aH, cL, av[nt], 0, 0, 0);
    }
  }

  float bb[8];
  #pragma unroll
  for (int nt = 0; nt < 8; ++nt) bb[nt] = bi[w*128 + nt*16 + lr];

  // n = w*128 + nt*16 + lr -> c = lr, k = w*8 + nt (8 consecutive k per lane)
  #pragma unroll
  for (int r = 0; r < 4; ++r){
    size_t node = nb + lg*4 + r;
    float4 p0 = {au[0][r]+bb[0], au[1][r]+bb[1], au[2][r]+bb[2], au[3][r]+bb[3]};
    float4 p1 = {au[4][r]+bb[4], au[5][r]+bb[5], au[6][r]+bb[6], au[7][r]+bb[7]};
    float* up = u_t + node*512 + lr*32 + w*8;
    *(float4*)up = p0;
    *(float4*)(up + 4) = p1;
    u32x4 vp;
    vp.x = pk2(av[0][r], av[1][r]); vp.y = pk2(av[2][r], av[3][r]);
    vp.z = pk2(av[4][r], av[5][r]); vp.w = pk2(av[6][r], av[7][r]);
    *(u32x4*)(v16_t + node*512 + lr*32 + w*8) = vp;
  }
}

// ---------------- gather3: transposed loads + LDS tj + pipelined edge loop ----------------
// Block = 4 nodes (waves) x 4 slots x 16 channels.
__global__ __launch_bounds__(256) void gather3_k(
    const float* __restrict__ u_t, const u16* __restrict__ v16_t,
    const float* __restrict__ frames, const float* __restrict__ tens_t,
    const float* __restrict__ gi, const float* __restrict__ bei,
    const uint32* __restrict__ start, const u16* __restrict__ srow,
    float* __restrict__ out)
{
  __shared__ float u_lds[4 * 576];    // [node][c*36+k]
  __shared__ float g_lds[576];        // [c*36+k]
  __shared__ float be_lds[576];
  __shared__ float st[16 * 152];      // tj staged [slot][m*16+k]

  const int t  = threadIdx.x;
  const int nl = t >> 6;
  const int sl = (t >> 4) & 3;
  const int c  = t & 15;
  const int nb = blockIdx.x * 4;
  const int n  = nb + nl;
  const int l  = t & 63;

  // stage u (transposed copy) + g/be (transposed)
  {
    const float* up = u_t + (size_t)n * 512 + l*8;
    float4 a = *(const float4*)up;
    float4 b = *(const float4*)(up + 4);
    int cc = l >> 2, kk = (l & 3) * 8;
    *(float4*)&u_lds[nl*576 + cc*36 + kk]     = a;
    *(float4*)&u_lds[nl*576 + cc*36 + kk + 4] = b;
    int n0 = t, n1 = t + 256;
    g_lds [(n0 & 15)*36 + (n0 >> 4)] = gi[n0];
    g_lds [(n1 & 15)*36 + (n1 >> 4)] = gi[n1];
    be_lds[(n0 & 15)*36 + (n0 >> 4)] = bei[n0];
    be_lds[(n1 & 15)*36 + (n1 >> 4)] = bei[n1];
  }
  __syncthreads();

  float Rn[9];
  {
    const float* fp = frames + (size_t)n * 9;
    #pragma unroll
    for (int m = 0; m < 9; ++m) Rn[m] = fp[m];
  }

  float o[9], wsum[16];
  #pragma unroll
  for (int m = 0; m < 9; ++m) o[m] = 0.f;
  #pragma unroll
  for (int k = 0; k < 16; ++k) wsum[k] = 0.f;

  const uint32 beg = (n == 0) ? 0u : start[n - 1];
  const uint32 end = start[n];
  const int stb = (nl*4 + sl) * 152;
  const int ub  = nl*576 + c*36;
  const int gb  = c*36;

  uint32 idx = beg + sl;
  int rcur = (idx < end) ? (int)srow[idx] : 0;

  u32x4 vb[4];
  float R[9];
  // prologue: stage tj(cur), load v(cur), Rj(cur) -> R
  {
    const float* tp = tens_t + (size_t)rcur * 144;
    #pragma unroll
    for (int q = 0; q < 3; ++q){
      int ch = c + q*16;
      if (ch < 36){
        float4 gv = *(const float4*)(tp + ch*4);
        *(float4*)&st[stb + ch*4] = gv;
      }
    }
    const u16* vp = v16_t + (size_t)rcur * 512 + c*32;
    #pragma unroll
    for (int q = 0; q < 4; ++q) vb[q] = *(const u32x4*)(vp + q*8);
    const float* Rj = frames + (size_t)rcur * 9;
    #pragma unroll
    for (int i = 0; i < 3; ++i)
      #pragma unroll
      for (int j = 0; j < 3; ++j)
        R[i*3+j] = Rn[i]*Rj[j] + Rn[3+i]*Rj[3+j] + Rn[6+i]*Rj[6+j];
  }

  while (idx < end){
    // ---- pass 1: LN stats ----
    float s = 0.f, q = 0.f;
    #pragma unroll
    for (int kq = 0; kq < 8; ++kq){
      float4 u4 = *(const float4*)&u_lds[ub + kq*4];
      uint32 w0 = vb[kq>>1][(kq&1)*2 + 0];
      uint32 w1 = vb[kq>>1][(kq&1)*2 + 1];
      float z0 = u4.x + bflo(w0), z1 = u4.y + bfhi(w0);
      float z2 = u4.z + bflo(w1), z3 = u4.w + bfhi(w1);
      s += (z0 + z1) + (z2 + z3);
      q += (z0*z0 + z1*z1) + (z2*z2 + z3*z3);
    }
    #pragma unroll
    for (int off = 1; off < 16; off <<= 1){ s += __shfl_xor(s, off); q += __shfl_xor(q, off); }
    float mu = s * (1.0f/512.0f);
    float rs = rsqrtf(q * (1.0f/512.0f) - mu*mu + 1e-5f);

    // ---- prefetch next: index + v ----
    uint32 idxn = idx + 4;
    int rnext = (idxn < end) ? (int)srow[idxn] : 0;
    u32x4 vb2[4];
    {
      const u16* vp = v16_t + (size_t)rnext * 512 + c*32;
      #pragma unroll
      for (int qq = 0; qq < 4; ++qq) vb2[qq] = *(const u32x4*)(vp + qq*8);
    }

    // ---- pass 2: w1 weights (k<16) -> wsum ----
    #pragma unroll
    for (int kq = 0; kq < 4; ++kq){
      float4 u4 = *(const float4*)&u_lds[ub + kq*4];
      float4 g4 = *(const float4*)&g_lds[gb + kq*4];
      float4 b4 = *(const float4*)&be_lds[gb + kq*4];
      uint32 w0 = vb[kq>>1][(kq&1)*2 + 0];
      uint32 w1 = vb[kq>>1][(kq&1)*2 + 1];
      wsum[kq*4+0] += sigmoidf_((u4.x + bflo(w0) - mu)*rs*g4.x + b4.x);
      wsum[kq*4+1] += sigmoidf_((u4.y + bfhi(w0) - mu)*rs*g4.y + b4.y);
      wsum[kq*4+2] += sigmoidf_((u4.z + bflo(w1) - mu)*rs*g4.z + b4.z);
      wsum[kq*4+3] += sigmoidf_((u4.w + bfhi(w1) - mu)*rs*g4.w + b4.w);
    }

    // ---- G contraction (k>=16): G[m] = sum_k tj[k][m] * w2[k] ----
    float G[9];
    #pragma unroll
    for (int m = 0; m < 9; ++m) G[m] = 0.f;
    #pragma unroll
    for (int kq = 0; kq < 4; ++kq){
      float4 u4 = *(const float4*)&u_lds[ub + 16 + kq*4];
      float4 g4 = *(const float4*)&g_lds[gb + 16 + kq*4];
      float4 b4 = *(const float4*)&be_lds[gb + 16 + kq*4];
      uint32 w0 = vb[2 + (kq>>1)][(kq&1)*2 + 0];
      uint32 w1 = vb[2 + (kq>>1)][(kq&1)*2 + 1];
      float wk0 = sigmoidf_((u4.x + bflo(w0) - mu)*rs*g4.x + b4.x);
      float wk1 = sigmoidf_((u4.y + bfhi(w0) - mu)*rs*g4.y + b4.y);
      float wk2 = sigmoidf_((u4.z + bflo(w1) - mu)*rs*g4.z + b4.z);
      float wk3 = sigmoidf_((u4.w + bfhi(w1) - mu)*rs*g4.w + b4.w);
      #pragma unroll
      for (int m = 0; m < 9; ++m){
        float4 sv = *(const float4*)&st[stb + m*16 + kq*4];
        G[m] += sv.x*wk0 + sv.y*wk1 + sv.z*wk2 + sv.w*wk3;
      }
    }

    // ---- stage next tj (overwrites st after reads; same-wave ordering) ----
    {
      const float* tp = tens_t + (size_t)rnext * 144;
      #pragma unroll
      for (int qq = 0; qq < 3; ++qq){
        int ch = c + qq*16;
        if (ch < 36){
          float4 gv = *(const float4*)(tp + ch*4);
          *(float4*)&st[stb + ch*4] = gv;
        }
      }
    }

    // ---- rotate: o += R @ G @ R ----
    {
      float A[9];
      #pragma unroll
      for (int i = 0; i < 3; ++i)
        #pragma unroll
        for (int j = 0; j < 3; ++j)
          A[i*3+j] = R[i*3+0]*G[0+j] + R[i*3+1]*G[3+j] + R[i*3+2]*G[6+j];
      #pragma unroll
      for (int i = 0; i < 3; ++i)
        #pragma unroll
        for (int j = 0; j < 3; ++j)
          o[i*3+j] += A[i*3+0]*R[0+j] + A[i*3+1]*R[3+j] + A[i*3+2]*R[6+j];
    }

    // ---- next R ----
    {
      const float* Rj = frames + (size_t)rnext * 9;
      #pragma unroll
      for (int i = 0; i < 3; ++i)
        #pragma unroll
        for (int j = 0; j < 3; ++j)
          R[i*3+j] = Rn[i]*Rj[j] + Rn[3+i]*Rj[3+j] + Rn[6+i]*Rj[6+j];
    }

    vb[0] = vb2[0]; vb[1] = vb2[1]; vb[2] = vb2[2]; vb[3] = vb2[3];
    idx = idxn;
  }

  // ---- reduce over slots ----
  #pragma unroll
  for (int m = 0; m < 9; ++m){
    o[m] += __shfl_xor(o[m], 16);
    o[m] += __shfl_xor(o[m], 32);
  }
  #pragma unroll
  for (int k = 0; k < 16; ++k){
    wsum[k] += __shfl_xor(wsum[k], 16);
    wsum[k] += __shfl_xor(wsum[k], 32);
  }

  // ---- ti part: o[m] += sum_k ti[k][m] * wsum[k] ----
  {
    const float* tt = tens_t + (size_t)n * 144;
    #pragma unroll
    for (int m = 0; m < 9; ++m){
      float4 a0 = *(const float4*)(tt + m*16);
      float4 a1 = *(const float4*)(tt + m*16 + 4);
      float4 a2 = *(const float4*)(tt + m*16 + 8);
      float4 a3 = *(const float4*)(tt + m*16 + 12);
      o[m] += a0.x*wsum[0] + a0.y*wsum[1] + a0.z*wsum[2] + a0.w*wsum[3]
            + a1.x*wsum[4] + a1.y*wsum[5] + a1.z*wsum[6] + a1.w*wsum[7]
            + a2.x*wsum[8] + a2.y*wsum[9] + a2.z*wsum[10]+ a2.w*wsum[11]
            + a3.x*wsum[12]+ a3.y*wsum[13]+ a3.z*wsum[14]+ a3.w*wsum[15];
    }
  }

  if (sl == 0){
    float s01 = 0.5f*(o[1]+o[3]), s02 = 0.5f*(o[2]+o[6]), s12 = 0.5f*(o[5]+o[7]);
    float* op = out + (size_t)n * D9 + c*9;
    op[0] = o[0]; op[1] = s01;  op[2] = s02;
    op[3] = s01;  op[4] = o[4]; op[5] = s12;
    op[6] = s02;  op[7] = s12;  op[8] = o[8];
  }
}

extern "C" void kernel_launch(void* const* d_in, const int* in_sizes, int n_in,
                              void* d_out, int out_size, void* d_ws, size_t ws_size,
                              hipStream_t stream) {
    const float* h      = (const float*)d_in[1];
    const float* frames = (const float*)d_in[2];
    const int*   ei     = (const int*)d_in[3];
    const float* W1  = (const float*)d_in[5];
    const float* b1  = (const float*)d_in[6];
    const float* g1  = (const float*)d_in[7];
    const float* be1 = (const float*)d_in[8];
    const float* W2  = (const float*)d_in[9];
    const float* b2  = (const float*)d_in[10];
    const float* g2  = (const float*)d_in[11];
    const float* be2 = (const float*)d_in[12];
    const float* Wi  = (const float*)d_in[13];
    const float* bi  = (const float*)d_in[14];
    const float* gi  = (const float*)d_in[15];
    const float* bei = (const float*)d_in[16];

    float* out = (float*)d_out;

    // ws layout (~110.9 MB; proven ws >= 140.68 MB):
    float*  u_t   = (float*)d_ws;                           // [N,512] f32 : 61,440,000
    u16*    v16_t = (u16*)  ((char*)d_ws + 61440000);       // [N,512] bf16: 30,720,000
    float*  tens_t= (float*)((char*)d_ws + 92160000);       // [N,144] f32 : 17,280,000
    u16*    Wq    = (u16*)  ((char*)d_ws + 109440000);      // 524,288
    u16*    W1s   = (u16*)  ((char*)d_ws + 109964288);      // 73,728
    u16*    W2s   = (u16*)  ((char*)d_ws + 110038016);      // 92,160
    uint32* start = (uint32*)((char*)d_ws + 110130176);     // 120,000
    u16*    srow  = (u16*)  ((char*)d_ws + 110250176);      // 600,000

    hipMemsetAsync(start, 0, NN * sizeof(uint32), stream);

    cvt_wq_k<<<256, 256, 0, stream>>>(Wi, Wq);
    cvt_w1s_k<<<72, 256, 0, stream>>>(W1, W1s);
    cvt_w2s_k<<<90, 256, 0, stream>>>(W2, W2s);
    tensor_init2_k<<<NN/16, 256, 0, stream>>>(h, W1s, W2s, b1, g1, be1, b2, g2, be2, tens_t);
    node_gemm_k<<<NN/16, 256, 0, stream>>>(h, Wq, bi, u_t, v16_t);
    hist_k<<<(EE + 255)/256, 256, 0, stream>>>(ei, start);
    scan_k<<<1, 1024, 0, stream>>>(start);
    scatter_k<<<(EE + 255)/256, 256, 0, stream>>>(ei, start, srow);
    gather3_k<<<NN/4, 256, 0, stream>>>(u_t, v16_t, frames, tens_t, gi, bei, start, srow, out);
}

// Round 10
// 652.938 us; speedup vs baseline: 4.9037x; 1.2045x over previous
//
#include <hip/hip_runtime.h>

#define NN 30000
#define EE 300000
#define HD 128
#define D9 144
#define ECHUNK 150000

typedef unsigned int uint32;
typedef unsigned short u16;
typedef __attribute__((ext_vector_type(8))) short short8;
typedef __attribute__((ext_vector_type(4))) float f32x4;
typedef __attribute__((ext_vector_type(4))) uint32 u32x4;

__device__ __forceinline__ float sigmoidf_(float x){ return 1.0f/(1.0f+__expf(-x)); }
__device__ __forceinline__ float siluf_(float x){ return x/(1.0f+__expf(-x)); }
__device__ __forceinline__ u16 f2bf(float f){
  uint32 u = __float_as_uint(f);
  return (u16)((u + 0x7fffu + ((u>>16)&1u)) >> 16);   // RNE
}
__device__ __forceinline__ float bf2f(u16 b){ return __uint_as_float(((uint32)b)<<16); }
__device__ __forceinline__ float bflo(uint32 u){ return __uint_as_float(u<<16); }
__device__ __forceinline__ float bfhi(uint32 u){ return __uint_as_float(u & 0xffff0000u); }
__device__ __forceinline__ uint32 pk2(float a, float b){ return (uint32)f2bf(a) | ((uint32)f2bf(b)<<16); }

// ---------------- Wi -> [WiL_hi | WiL_lo | WiR_hi | WiR_lo], each [512x128] ----------------
__global__ __launch_bounds__(256) void cvt_wq_k(const float* __restrict__ Wi, u16* __restrict__ Wq){
  int i = blockIdx.x*256 + threadIdx.x;
  if (i < 512*128){
    int n = i >> 7, k = i & 127;
    float xl = Wi[n*256 + k];
    float xr = Wi[n*256 + 128 + k];
    u16 lh = f2bf(xl);
    Wq[i]          = lh;
    Wq[65536 + i]  = f2bf(xl - bf2f(lh));
    u16 rh = f2bf(xr);
    Wq[131072 + i] = rh;
    Wq[196608 + i] = f2bf(xr - bf2f(rh));
  }
}

// ---------------- W1 [144x128] -> hi/lo ----------------
__global__ __launch_bounds__(256) void cvt_w1s_k(const float* __restrict__ W1, u16* __restrict__ W1s){
  int i = blockIdx.x*256 + threadIdx.x;
  if (i < 144*128){
    float x = W1[i];
    u16 hh = f2bf(x);
    W1s[i] = hh;
    W1s[18432 + i] = f2bf(x - bf2f(hh));
  }
}
// ---------------- W2 [144x144] -> hi/lo padded [144x160] ----------------
__global__ __launch_bounds__(256) void cvt_w2s_k(const float* __restrict__ W2, u16* __restrict__ W2s){
  int i = blockIdx.x*256 + threadIdx.x;
  if (i < 144*160){
    int r = i / 160, k = i - r*160;
    float x = (k < 144) ? W2[r*144 + k] : 0.f;
    u16 hh = f2bf(x);
    W2s[i] = hh;
    W2s[23040 + i] = f2bf(x - bf2f(hh));
  }
}
// ---------------- gi/bei -> transposed gt/bet [c*32+k] ----------------
__global__ __launch_bounds__(256) void cvt_gt_k(const float* __restrict__ gi, const float* __restrict__ bei,
                                                float* __restrict__ gt, float* __restrict__ bet){
  int i = blockIdx.x*256 + threadIdx.x;
  if (i < 512){
    int c = i & 15, k = i >> 4;
    gt [c*32 + k] = gi[i];
    bet[c*32 + k] = bei[i];
  }
}

// ---------------- CSR build: hist -> scan -> scatter ----------------
__global__ __launch_bounds__(256) void hist_k(const int* __restrict__ ei, uint32* __restrict__ start){
  int e = blockIdx.x*256 + threadIdx.x;
  if (e < EE){
    int col = ei[EE + e];
    col = col < 0 ? 0 : (col >= NN ? NN-1 : col);
    atomicAdd(&start[col], 1u);
  }
}

__global__ __launch_bounds__(1024) void scan_k(uint32* __restrict__ start){
  __shared__ uint32 part[1024];
  const int t = threadIdx.x;
  const int base = t * 30;
  uint32 loc[30];
  uint32 s = 0;
  #pragma unroll
  for (int i = 0; i < 30; ++i){
    int idx = base + i;
    uint32 cv = (idx < NN) ? start[idx] : 0u;
    loc[i] = s;
    s += cv;
  }
  part[t] = s;
  __syncthreads();
  for (int off = 1; off < 1024; off <<= 1){
    uint32 add = (t >= off) ? part[t - off] : 0u;
    __syncthreads();
    part[t] += add;
    __syncthreads();
  }
  uint32 pre = (t == 0) ? 0u : part[t - 1];
  #pragma unroll
  for (int i = 0; i < 30; ++i){
    int idx = base + i;
    if (idx < NN) start[idx] = pre + loc[i];
  }
}

__global__ __launch_bounds__(256) void scatter_k(const int* __restrict__ ei,
                                                 uint32* __restrict__ start,
                                                 u16* __restrict__ srow, u16* __restrict__ scol){
  int e = blockIdx.x*256 + threadIdx.x;
  if (e < EE){
    int row = ei[e];
    row = row < 0 ? 0 : (row >= NN ? NN-1 : row);
    int col = ei[EE + e];
    col = col < 0 ? 0 : (col >= NN ? NN-1 : col);
    uint32 pos = atomicAdd(&start[col], 1u);   // start becomes end(col)
    srow[pos] = (u16)row;
    scol[pos] = (u16)col;
  }
}

// ---------------- tensor_init2: MFMA bf16x3, writes tens_t[n][m*16+c] ----------------
__global__ __launch_bounds__(256) void tensor_init2_k(
    const float* __restrict__ h,
    const u16* __restrict__ W1s, const u16* __restrict__ W2s,
    const float* __restrict__ b1, const float* __restrict__ g1, const float* __restrict__ be1,
    const float* __restrict__ b2, const float* __restrict__ g2, const float* __restrict__ be2,
    float* __restrict__ tens_t)
{
  __shared__ float t1s[16 * 164];
  __shared__ float pool[160];

  const int t = threadIdx.x;
  const int w = t >> 6, l = t & 63, lr = l & 15, lg = l >> 4;
  const int nb = blockIdx.x * 16;
  const int ntile = (w == 0) ? 3 : 2;
  int tiles[3]; tiles[0] = 2*w; tiles[1] = 2*w + 1; tiles[2] = 8;

  f32x4 acc[3];
  #pragma unroll
  for (int ti = 0; ti < 3; ++ti) acc[ti] = (f32x4){0,0,0,0};
  {
    const float* qA = h + (size_t)(nb + lr) * HD + lg*8;
    #pragma unroll
    for (int ks = 0; ks < 4; ++ks){
      float4 x0 = *(const float4*)(qA + ks*32);
      float4 x1 = *(const float4*)(qA + ks*32 + 4);
      float xs[8] = {x0.x, x0.y, x0.z, x0.w, x1.x, x1.y, x1.z, x1.w};
      short8 aH, aL;
      #pragma unroll
      for (int j = 0; j < 8; ++j){
        u16 hh = f2bf(xs[j]);
        aH[j] = (short)hh;
        aL[j] = (short)f2bf(xs[j] - bf2f(hh));
      }
      for (int ti = 0; ti < ntile; ++ti){
        const u16* b = W1s + (tiles[ti]*16 + lr)*128 + lg*8 + ks*32;
        short8 bH = *(const short8*)b;
        short8 bL = *(const short8*)(b + 18432);
        acc[ti] = __builtin_amdgcn_mfma_f32_16x16x32_bf16(aH, bH, acc[ti], 0, 0, 0);
        acc[ti] = __builtin_amdgcn_mfma_f32_16x16x32_bf16(aL, bH, acc[ti], 0, 0, 0);
        acc[ti] = __builtin_amdgcn_mfma_f32_16x16x32_bf16(aH, bL, acc[ti], 0, 0, 0);
      }
    }
  }
  for (int ti = 0; ti < ntile; ++ti){
    float bb = b1[tiles[ti]*16 + lr];
    #pragma unroll
    for (int r = 0; r < 4; ++r) acc[ti][r] += bb;
  }
  {
    float ps[4], pq[4];
    #pragma unroll
    for (int r = 0; r < 4; ++r){
      float s = 0.f, q = 0.f;
      for (int ti = 0; ti < ntile; ++ti){ s += acc[ti][r]; q += acc[ti][r]*acc[ti][r]; }
      ps[r] = s; pq[r] = q;
    }
    #pragma unroll
    for (int off = 1; off < 16; off <<= 1)
      #pragma unroll
      for (int r = 0; r < 4; ++r){ ps[r] += __shfl_xor(ps[r], off); pq[r] += __shfl_xor(pq[r], off); }
    if (lr == 0){
      #pragma unroll
      for (int r = 0; r < 4; ++r){
        pool[w*32 + (lg*4 + r)*2 + 0] = ps[r];
        pool[w*32 + (lg*4 + r)*2 + 1] = pq[r];
      }
    }
  }
  __syncthreads();
  if (t < 16){
    float s = pool[t*2] + pool[32 + t*2] + pool[64 + t*2] + pool[96 + t*2];
    float q = pool[t*2+1] + pool[32 + t*2+1] + pool[64 + t*2+1] + pool[96 + t*2+1];
    float mu = s * (1.0f/144.0f);
    pool[128 + t] = mu;
    pool[144 + t] = rsqrtf(q * (1.0f/144.0f) - mu*mu + 1e-5f);
  }
  __syncthreads();
  for (int ti = 0; ti < ntile; ++ti){
    int col = tiles[ti]*16 + lr;
    float gg = g1[col], bb = be1[col];
    #pragma unroll
    for (int r = 0; r < 4; ++r){
      int node = lg*4 + r;
      float mu = pool[128 + node], rs = pool[144 + node];
      t1s[node*164 + col] = siluf_((acc[ti][r] - mu) * rs * gg + bb);
    }
  }
  t1s[(t >> 4)*164 + 144 + (t & 15)] = 0.f;
  __syncthreads();

  #pragma unroll
  for (int ti = 0; ti < 3; ++ti) acc[ti] = (f32x4){0,0,0,0};
  #pragma unroll
  for (int ks = 0; ks < 5; ++ks){
    float4 x0 = *(const float4*)&t1s[lr*164 + lg*8 + ks*32];
    float4 x1 = *(const float4*)&t1s[lr*164 + lg*8 + ks*32 + 4];
    float xs[8] = {x0.x, x0.y, x0.z, x0.w, x1.x, x1.y, x1.z, x1.w};
    short8 aH, aL;
    #pragma unroll
    for (int j = 0; j < 8; ++j){
      u16 hh = f2bf(xs[j]);
      aH[j] = (short)hh;
      aL[j] = (short)f2bf(xs[j] - bf2f(hh));
    }
    for (int ti = 0; ti < ntile; ++ti){
      const u16* b = W2s + (tiles[ti]*16 + lr)*160 + lg*8 + ks*32;
      short8 bH = *(const short8*)b;
      short8 bL = *(const short8*)(b + 23040);
      acc[ti] = __builtin_amdgcn_mfma_f32_16x16x32_bf16(aH, bH, acc[ti], 0, 0, 0);
      acc[ti] = __builtin_amdgcn_mfma_f32_16x16x32_bf16(aL, bH, acc[ti], 0, 0, 0);
      acc[ti] = __builtin_amdgcn_mfma_f32_16x16x32_bf16(aH, bL, acc[ti], 0, 0, 0);
    }
  }
  for (int ti = 0; ti < ntile; ++ti){
    float bb = b2[tiles[ti]*16 + lr];
    #pragma unroll
    for (int r = 0; r < 4; ++r) acc[ti][r] += bb;
  }
  __syncthreads();
  {
    float ps[4], pq[4];
    #pragma unroll
    for (int r = 0; r < 4; ++r){
      float s = 0.f, q = 0.f;
      for (int ti = 0; ti < ntile; ++ti){ s += acc[ti][r]; q += acc[ti][r]*acc[ti][r]; }
      ps[r] = s; pq[r] = q;
    }
    #pragma unroll
    for (int off = 1; off < 16; off <<= 1)
      #pragma unroll
      for (int r = 0; r < 4; ++r){ ps[r] += __shfl_xor(ps[r], off); pq[r] += __shfl_xor(pq[r], off); }
    if (lr == 0){
      #pragma unroll
      for (int r = 0; r < 4; ++r){
        pool[w*32 + (lg*4 + r)*2 + 0] = ps[r];
        pool[w*32 + (lg*4 + r)*2 + 1] = pq[r];
      }
    }
  }
  __syncthreads();
  if (t < 16){
    float s = pool[t*2] + pool[32 + t*2] + pool[64 + t*2] + pool[96 + t*2];
    float q = pool[t*2+1] + pool[32 + t*2+1] + pool[64 + t*2+1] + pool[96 + t*2+1];
    float mu = s * (1.0f/144.0f);
    pool[128 + t] = mu;
    pool[144 + t] = rsqrtf(q * (1.0f/144.0f) - mu*mu + 1e-5f);
  }
  __syncthreads();
  for (int ti = 0; ti < ntile; ++ti){
    int col = tiles[ti]*16 + lr;
    float gg = g2[col], bb = be2[col];
    int c = col / 9, m = col - c*9;
    #pragma unroll
    for (int r = 0; r < 4; ++r){
      int node = lg*4 + r;
      float mu = pool[128 + node], rs = pool[144 + node];
      float val = siluf_((acc[ti][r] - mu) * rs * gg + bb);
      tens_t[(size_t)(nb + node)*144 + m*16 + c] = val;
    }
  }
}

// ---------------- node_gemm: uu_t[n][c*32+k] bf16 (+bi), v16_t[n][c*32+k] bf16 ----------------
__global__ __launch_bounds__(256) void node_gemm_k(
    const float* __restrict__ h, const u16* __restrict__ Wq,
    const float* __restrict__ bi,
    u16* __restrict__ uu_t, u16* __restrict__ v16_t)
{
  const int t = threadIdx.x;
  const int w = t >> 6, l = t & 63, lr = l & 15, lg = l >> 4;
  const int nb = blockIdx.x * 16;

  const float* qA = h + (size_t)(nb + lr) * HD + lg*8;
  f32x4 au[8], av[8];
  #pragma unroll
  for (int nt = 0; nt < 8; ++nt){ au[nt] = (f32x4){0,0,0,0}; av[nt] = (f32x4){0,0,0,0}; }

  #pragma unroll
  for (int ks = 0; ks < 4; ++ks){
    float4 x0 = *(const float4*)(qA + ks*32);
    float4 x1 = *(const float4*)(qA + ks*32 + 4);
    float xs[8] = {x0.x, x0.y, x0.z, x0.w, x1.x, x1.y, x1.z, x1.w};
    short8 aH, aL;
    #pragma unroll
    for (int j = 0; j < 8; ++j){
      u16 hh = f2bf(xs[j]);
      aH[j] = (short)hh;
      aL[j] = (short)f2bf(xs[j] - bf2f(hh));
    }
    #pragma unroll
    for (int nt = 0; nt < 8; ++nt){
      const u16* bu = Wq + (w*128 + nt*16 + lr)*128 + lg*8 + ks*32;
      short8 bH = *(const short8*)bu;
      short8 bL = *(const short8*)(bu + 65536);
      au[nt] = __builtin_amdgcn_mfma_f32_16x16x32_bf16(aH, bH, au[nt], 0, 0, 0);
      au[nt] = __builtin_amdgcn_mfma_f32_16x16x32_bf16(aL, bH, au[nt], 0, 0, 0);
      au[nt] = __builtin_amdgcn_mfma_f32_16x16x32_bf16(aH, bL, au[nt], 0, 0, 0);
      const u16* bv = bu + 131072;
      short8 cH = *(const short8*)bv;
      short8 cL = *(const short8*)(bv + 65536);
      av[nt] = __builtin_amdgcn_mfma_f32_16x16x32_bf16(aH, cH, av[nt], 0, 0, 0);
      av[nt] = __builtin_amdgcn_mfma_f32_16x16x32_bf16(aL, cH, av[nt], 0, 0, 0);
      av[nt] = __builtin_amdgcn_mfma_f32_16x16x32_bf16(aH, cL, av[nt], 0, 0, 0);
    }
  }

  float bb[8];
  #pragma unroll
  for (int nt = 0; nt < 8; ++nt) bb[nt] = bi[w*128 + nt*16 + lr];

  // n = w*128 + nt*16 + lr -> c = lr, k = w*8 + nt
  #pragma unroll
  for (int r = 0; r < 4; ++r){
    size_t node = nb + lg*4 + r;
    u32x4 pu;
    pu.x = pk2(au[0][r]+bb[0], au[1][r]+bb[1]);
    pu.y = pk2(au[2][r]+bb[2], au[3][r]+bb[3]);
    pu.z = pk2(au[4][r]+bb[4], au[5][r]+bb[5]);
    pu.w = pk2(au[6][r]+bb[6], au[7][r]+bb[7]);
    *(u32x4*)(uu_t + node*512 + lr*32 + w*8) = pu;
    u32x4 pv;
    pv.x = pk2(av[0][r], av[1][r]); pv.y = pk2(av[2][r], av[3][r]);
    pv.z = pk2(av[4][r], av[5][r]); pv.w = pk2(av[6][r], av[7][r]);
    *(u32x4*)(v16_t + node*512 + lr*32 + w*8) = pv;
  }
}

// ---------------- edge_par: one thread per (edge, channel); no loops/LDS/barriers ----------------
// Writes per-edge symmetrized contribution tn[eloc][c][6] f32.
__global__ __launch_bounds__(256) void edge_par_k(
    const u16* __restrict__ uu_t, const u16* __restrict__ v16_t,
    const float* __restrict__ frames, const float* __restrict__ tens_t,
    const float* __restrict__ gt, const float* __restrict__ bet,
    const u16* __restrict__ srow, const u16* __restrict__ scol,
    int ebase, float* __restrict__ tn)
{
  const int t = threadIdx.x;
  const int le = t >> 4, c = t & 15;
  const int eloc = blockIdx.x*16 + le;
  const size_t idx = (size_t)ebase + eloc;
  const int row = (int)srow[idx], col = (int)scol[idx];

  // ---- z[k] = u[col][c,k] + v[row][c,k] ----
  float z[32];
  {
    const u16* up = uu_t + (size_t)col*512 + c*32;
    const u16* vp = v16_t + (size_t)row*512 + c*32;
    #pragma unroll
    for (int q = 0; q < 4; ++q){
      u32x4 ua = *(const u32x4*)(up + q*8);
      u32x4 va = *(const u32x4*)(vp + q*8);
      z[q*8+0] = bflo(ua.x)+bflo(va.x); z[q*8+1] = bfhi(ua.x)+bfhi(va.x);
      z[q*8+2] = bflo(ua.y)+bflo(va.y); z[q*8+3] = bfhi(ua.y)+bfhi(va.y);
      z[q*8+4] = bflo(ua.z)+bflo(va.z); z[q*8+5] = bfhi(ua.z)+bfhi(va.z);
      z[q*8+6] = bflo(ua.w)+bflo(va.w); z[q*8+7] = bfhi(ua.w)+bfhi(va.w);
    }
  }

  // ---- LN over 512 (32/lane x 16 lanes of this edge) ----
  float s = 0.f, q2 = 0.f;
  #pragma unroll
  for (int k = 0; k < 32; ++k){ s += z[k]; q2 += z[k]*z[k]; }
  #pragma unroll
  for (int off = 1; off < 16; off <<= 1){ s += __shfl_xor(s, off); q2 += __shfl_xor(q2, off); }
  float mu = s * (1.0f/512.0f);
  float rs = rsqrtf(q2 * (1.0f/512.0f) - mu*mu + 1e-5f);

  // ---- w[k] = sigmoid(LN(z)) in place ----
  {
    const float* gp = gt  + c*32;
    const float* bp = bet + c*32;
    #pragma unroll
    for (int kq = 0; kq < 8; ++kq){
      float4 g4 = *(const float4*)(gp + kq*4);
      float4 b4 = *(const float4*)(bp + kq*4);
      z[kq*4+0] = sigmoidf_((z[kq*4+0]-mu)*rs*g4.x + b4.x);
      z[kq*4+1] = sigmoidf_((z[kq*4+1]-mu)*rs*g4.y + b4.y);
      z[kq*4+2] = sigmoidf_((z[kq*4+2]-mu)*rs*g4.z + b4.z);
      z[kq*4+3] = sigmoidf_((z[kq*4+3]-mu)*rs*g4.w + b4.w);
    }
  }

  // ---- ti-part (k<16) and G (k>=16), broadcast float4 reads ----
  float o[9], G[9];
  {
    const float* ti = tens_t + (size_t)col*144;
    const float* tj = tens_t + (size_t)row*144;
    #pragma unroll
    for (int m = 0; m < 9; ++m){
      float a = 0.f, g = 0.f;
      #pragma unroll
      for (int kq = 0; kq < 4; ++kq){
        float4 t4 = *(const float4*)(ti + m*16 + kq*4);
        a += t4.x*z[kq*4+0] + t4.y*z[kq*4+1] + t4.z*z[kq*4+2] + t4.w*z[kq*4+3];
        float4 u4 = *(const float4*)(tj + m*16 + kq*4);
        g += u4.x*z[16+kq*4+0] + u4.y*z[16+kq*4+1] + u4.z*z[16+kq*4+2] + u4.w*z[16+kq*4+3];
      }
      o[m] = a; G[m] = g;
    }
  }

  // ---- R = Ri^T Rj ; o += R G R ----
  {
    const float* Ri = frames + (size_t)col*9;
    const float* Rj = frames + (size_t)row*9;
    float R[9];
    #pragma unroll
    for (int i = 0; i < 3; ++i)
      #pragma unroll
      for (int j = 0; j < 3; ++j)
        R[i*3+j] = Ri[i]*Rj[j] + Ri[3+i]*Rj[3+j] + Ri[6+i]*Rj[6+j];
    float A[9];
    #pragma unroll
    for (int i = 0; i < 3; ++i)
      #pragma unroll
      for (int j = 0; j < 3; ++j)
        A[i*3+j] = R[i*3+0]*G[0+j] + R[i*3+1]*G[3+j] + R[i*3+2]*G[6+j];
    #pragma unroll
    for (int i = 0; i < 3; ++i)
      #pragma unroll
      for (int j = 0; j < 3; ++j)
        o[i*3+j] += A[i*3+0]*R[0+j] + A[i*3+1]*R[3+j] + A[i*3+2]*R[6+j];
  }

  // ---- symmetrize -> 6 values, store 24 B ----
  float s01 = 0.5f*(o[1]+o[3]), s02 = 0.5f*(o[2]+o[6]), s12 = 0.5f*(o[5]+o[7]);
  float* tp = tn + (size_t)eloc*96 + c*6;
  float2 w0 = {o[0], s01}, w1 = {s02, o[4]}, w2 = {s12, o[8]};
  *(float2*)tp = w0;
  *(float2*)(tp+2) = w1;
  *(float2*)(tp+4) = w2;
}

// ---------------- segsum: thread per (node, channel); sequential CSR-range sum ----------------
__global__ __launch_bounds__(256) void segsum_k(
    const float* __restrict__ tn, const uint32* __restrict__ start,
    uint32 ebase, uint32 eend, int first, float* __restrict__ out)
{
  int tid = blockIdx.x*256 + threadIdx.x;
  if (tid >= NN*16) return;
  int n = tid >> 4, c = tid & 15;
  uint32 beg = (n == 0) ? 0u : start[n-1];
  uint32 end = start[n];
  uint32 b = beg > ebase ? beg : ebase;
  uint32 e = end < eend ? end : eend;

  float* op = out + (size_t)n*144 + c*9;
  float a0, a1, a2, a3, a4, a5;
  if (first){ a0=a1=a2=a3=a4=a5=0.f; }
  else { a0=op[0]; a1=op[1]; a2=op[2]; a3=op[4]; a4=op[5]; a5=op[8]; }

  for (uint32 i = b; i < e; ++i){
    const float* tp = tn + (size_t)(i - ebase)*96 + c*6;
    float2 x0 = *(const float2*)tp;
    float2 x1 = *(const float2*)(tp+2);
    float2 x2 = *(const float2*)(tp+4);
    a0 += x0.x; a1 += x0.y; a2 += x1.x; a3 += x1.y; a4 += x2.x; a5 += x2.y;
  }

  op[0] = a0; op[1] = a1; op[2] = a2;
  op[3] = a1; op[4] = a3; op[5] = a4;
  op[6] = a2; op[7] = a4; op[8] = a5;
}

extern "C" void kernel_launch(void* const* d_in, const int* in_sizes, int n_in,
                              void* d_out, int out_size, void* d_ws, size_t ws_size,
                              hipStream_t stream) {
    const float* h      = (const float*)d_in[1];
    const float* frames = (const float*)d_in[2];
    const int*   ei     = (const int*)d_in[3];
    const float* W1  = (const float*)d_in[5];
    const float* b1  = (const float*)d_in[6];
    const float* g1  = (const float*)d_in[7];
    const float* be1 = (const float*)d_in[8];
    const float* W2  = (const float*)d_in[9];
    const float* b2  = (const float*)d_in[10];
    const float* g2  = (const float*)d_in[11];
    const float* be2 = (const float*)d_in[12];
    const float* Wi  = (const float*)d_in[13];
    const float* bi  = (const float*)d_in[14];
    const float* gi  = (const float*)d_in[15];
    const float* bei = (const float*)d_in[16];

    float* out = (float*)d_out;

    // ws layout (138.33 MB <= proven 140.68 MB):
    u16*    uu_t  = (u16*)d_ws;                             // [N,512] bf16: 30,720,000
    u16*    v16_t = (u16*)  ((char*)d_ws + 30720000);       // [N,512] bf16: 30,720,000
    float*  tens_t= (float*)((char*)d_ws + 61440000);       // [N,144] f32 : 17,280,000
    u16*    Wq    = (u16*)  ((char*)d_ws + 78720000);       // 524,288
    u16*    W1s   = (u16*)  ((char*)d_ws + 79244288);       // 73,728
    u16*    W2s   = (u16*)  ((char*)d_ws + 79318016);       // 92,160
    float*  gt    = (float*)((char*)d_ws + 79410176);       // 2,048
    float*  bet   = (float*)((char*)d_ws + 79412224);       // 2,048
    uint32* start = (uint32*)((char*)d_ws + 79414272);      // 120,000
    u16*    srow  = (u16*)  ((char*)d_ws + 79534272);       // 600,000
    u16*    scol  = (u16*)  ((char*)d_ws + 80134272);       // 600,000
    float*  tn    = (float*)((char*)d_ws + 80734272);       // [ECHUNK,16,6] f32: 57,600,000

    hipMemsetAsync(start, 0, NN * sizeof(uint32), stream);

    cvt_wq_k<<<256, 256, 0, stream>>>(Wi, Wq);
    cvt_w1s_k<<<72, 256, 0, stream>>>(W1, W1s);
    cvt_w2s_k<<<90, 256, 0, stream>>>(W2, W2s);
    cvt_gt_k<<<2, 256, 0, stream>>>(gi, bei, gt, bet);
    tensor_init2_k<<<NN/16, 256, 0, stream>>>(h, W1s, W2s, b1, g1, be1, b2, g2, be2, tens_t);
    node_gemm_k<<<NN/16, 256, 0, stream>>>(h, Wq, bi, uu_t, v16_t);
    hist_k<<<(EE + 255)/256, 256, 0, stream>>>(ei, start);
    scan_k<<<1, 1024, 0, stream>>>(start);
    scatter_k<<<(EE + 255)/256, 256, 0, stream>>>(ei, start, srow, scol);

    // chunk 0: edges [0, 150000)
    edge_par_k<<<ECHUNK/16, 256, 0, stream>>>(uu_t, v16_t, frames, tens_t, gt, bet, srow, scol, 0, tn);
    segsum_k<<<(NN*16 + 255)/256, 256, 0, stream>>>(tn, start, 0u, (uint32)ECHUNK, 1, out);
    // chunk 1: edges [150000, 300000)
    edge_par_k<<<ECHUNK/16, 256, 0, stream>>>(uu_t, v16_t, frames, tens_t, gt, bet, srow, scol, ECHUNK, tn);
    segsum_k<<<(NN*16 + 255)/256, 256, 0, stream>>>(tn, start, (uint32)ECHUNK, (uint32)EE, 0, out);
}

// Round 11
// 610.329 us; speedup vs baseline: 5.2460x; 1.0698x over previous
//
#include <hip/hip_runtime.h>

#define NN 30000
#define EE 300000
#define HD 128
#define D9 144

typedef unsigned int uint32;
typedef unsigned short u16;
typedef __attribute__((ext_vector_type(8))) short short8;
typedef __attribute__((ext_vector_type(4))) float f32x4;
typedef __attribute__((ext_vector_type(4))) uint32 u32x4;

__device__ __forceinline__ float sigmoidf_(float x){ return 1.0f/(1.0f+__expf(-x)); }
__device__ __forceinline__ float siluf_(float x){ return x/(1.0f+__expf(-x)); }
__device__ __forceinline__ u16 f2bf(float f){
  uint32 u = __float_as_uint(f);
  return (u16)((u + 0x7fffu + ((u>>16)&1u)) >> 16);   // RNE
}
__device__ __forceinline__ float bf2f(u16 b){ return __uint_as_float(((uint32)b)<<16); }
__device__ __forceinline__ float bflo(uint32 u){ return __uint_as_float(u<<16); }
__device__ __forceinline__ float bfhi(uint32 u){ return __uint_as_float(u & 0xffff0000u); }
__device__ __forceinline__ uint32 pk2(float a, float b){ return (uint32)f2bf(a) | ((uint32)f2bf(b)<<16); }

// ---------------- fused converter: Wq | W1s | W2s | gt/bet ----------------
__global__ __launch_bounds__(256) void cvt_all_k(
    const float* __restrict__ Wi, u16* __restrict__ Wq,
    const float* __restrict__ W1, u16* __restrict__ W1s,
    const float* __restrict__ W2, u16* __restrict__ W2s,
    const float* __restrict__ gi, const float* __restrict__ bei,
    float* __restrict__ gt, float* __restrict__ bet)
{
  int i = blockIdx.x*256 + threadIdx.x;
  if (i < 512*128){
    int n = i >> 7, k = i & 127;
    float xl = Wi[n*256 + k];
    float xr = Wi[n*256 + 128 + k];
    u16 lh = f2bf(xl);
    Wq[i]          = lh;
    Wq[65536 + i]  = f2bf(xl - bf2f(lh));
    u16 rh = f2bf(xr);
    Wq[131072 + i] = rh;
    Wq[196608 + i] = f2bf(xr - bf2f(rh));
  }
  if (i < 144*128){
    float x = W1[i];
    u16 hh = f2bf(x);
    W1s[i] = hh;
    W1s[18432 + i] = f2bf(x - bf2f(hh));
  }
  if (i < 144*160){
    int r = i / 160, k = i - r*160;
    float x = (k < 144) ? W2[r*144 + k] : 0.f;
    u16 hh = f2bf(x);
    W2s[i] = hh;
    W2s[23040 + i] = f2bf(x - bf2f(hh));
  }
  if (i < 512){
    int c = i & 15, k = i >> 4;
    gt [c*32 + k] = gi[i];
    bet[c*32 + k] = bei[i];
  }
}

// ---------------- CSR build: hist -> scan -> scatter ----------------
__global__ __launch_bounds__(256) void hist_k(const int* __restrict__ ei, uint32* __restrict__ start){
  int e = blockIdx.x*256 + threadIdx.x;
  if (e < EE){
    int col = ei[EE + e];
    col = col < 0 ? 0 : (col >= NN ? NN-1 : col);
    atomicAdd(&start[col], 1u);
  }
}

__global__ __launch_bounds__(1024) void scan_k(uint32* __restrict__ start){
  __shared__ uint32 part[1024];
  const int t = threadIdx.x;
  const int base = t * 30;
  uint32 loc[30];
  uint32 s = 0;
  #pragma unroll
  for (int i = 0; i < 30; ++i){
    int idx = base + i;
    uint32 cv = (idx < NN) ? start[idx] : 0u;
    loc[i] = s;
    s += cv;
  }
  part[t] = s;
  __syncthreads();
  for (int off = 1; off < 1024; off <<= 1){
    uint32 add = (t >= off) ? part[t - off] : 0u;
    __syncthreads();
    part[t] += add;
    __syncthreads();
  }
  uint32 pre = (t == 0) ? 0u : part[t - 1];
  #pragma unroll
  for (int i = 0; i < 30; ++i){
    int idx = base + i;
    if (idx < NN) start[idx] = pre + loc[i];
  }
}

__global__ __launch_bounds__(256) void scatter_k(const int* __restrict__ ei,
                                                 uint32* __restrict__ start,
                                                 u16* __restrict__ srow, u16* __restrict__ scol){
  int e = blockIdx.x*256 + threadIdx.x;
  if (e < EE){
    int row = ei[e];
    row = row < 0 ? 0 : (row >= NN ? NN-1 : row);
    int col = ei[EE + e];
    col = col < 0 ? 0 : (col >= NN ? NN-1 : col);
    uint32 pos = atomicAdd(&start[col], 1u);   // start becomes end(col)
    srow[pos] = (u16)row;
    scol[pos] = (u16)col;
  }
}

// ---------------- node_all: fused u/v GEMM + tensor_init (shared h A-fragments) ----------------
// 16 nodes/block, 4 waves.
__global__ __launch_bounds__(256) void node_all_k(
    const float* __restrict__ h, const u16* __restrict__ Wq,
    const float* __restrict__ bi,
    const u16* __restrict__ W1s, const u16* __restrict__ W2s,
    const float* __restrict__ b1, const float* __restrict__ g1, const float* __restrict__ be1,
    const float* __restrict__ b2, const float* __restrict__ g2, const float* __restrict__ be2,
    u16* __restrict__ uu_t, u16* __restrict__ v16_t, float* __restrict__ tens_t)
{
  __shared__ float t1s[16 * 164];
  __shared__ float pool[160];

  const int t = threadIdx.x;
  const int w = t >> 6, l = t & 63, lr = l & 15, lg = l >> 4;
  const int nb = blockIdx.x * 16;
  const int ntile = (w == 0) ? 3 : 2;
  int tiles[3]; tiles[0] = 2*w; tiles[1] = 2*w + 1; tiles[2] = 8;

  // ---- load h once, convert A fragments for all 4 K-steps ----
  short8 aH[4], aL[4];
  {
    const float* qA = h + (size_t)(nb + lr) * HD + lg*8;
    #pragma unroll
    for (int ks = 0; ks < 4; ++ks){
      float4 x0 = *(const float4*)(qA + ks*32);
      float4 x1 = *(const float4*)(qA + ks*32 + 4);
      float xs[8] = {x0.x, x0.y, x0.z, x0.w, x1.x, x1.y, x1.z, x1.w};
      #pragma unroll
      for (int j = 0; j < 8; ++j){
        u16 hh = f2bf(xs[j]);
        aH[ks][j] = (short)hh;
        aL[ks][j] = (short)f2bf(xs[j] - bf2f(hh));
      }
    }
  }

  // ================= part 1: u = WiL@h + bi, v = WiR@h =================
  {
    f32x4 au[8], av[8];
    #pragma unroll
    for (int nt = 0; nt < 8; ++nt){ au[nt] = (f32x4){0,0,0,0}; av[nt] = (f32x4){0,0,0,0}; }
    #pragma unroll
    for (int ks = 0; ks < 4; ++ks){
      #pragma unroll
      for (int nt = 0; nt < 8; ++nt){
        const u16* bu = Wq + (w*128 + nt*16 + lr)*128 + lg*8 + ks*32;
        short8 bH = *(const short8*)bu;
        short8 bL = *(const short8*)(bu + 65536);
        au[nt] = __builtin_amdgcn_mfma_f32_16x16x32_bf16(aH[ks], bH, au[nt], 0, 0, 0);
        au[nt] = __builtin_amdgcn_mfma_f32_16x16x32_bf16(aL[ks], bH, au[nt], 0, 0, 0);
        au[nt] = __builtin_amdgcn_mfma_f32_16x16x32_bf16(aH[ks], bL, au[nt], 0, 0, 0);
        const u16* bv = bu + 131072;
        short8 cH = *(const short8*)bv;
        short8 cL = *(const short8*)(bv + 65536);
        av[nt] = __builtin_amdgcn_mfma_f32_16x16x32_bf16(aH[ks], cH, av[nt], 0, 0, 0);
        av[nt] = __builtin_amdgcn_mfma_f32_16x16x32_bf16(aL[ks], cH, av[nt], 0, 0, 0);
        av[nt] = __builtin_amdgcn_mfma_f32_16x16x32_bf16(aH[ks], cL, av[nt], 0, 0, 0);
      }
    }
    float bb[8];
    #pragma unroll
    for (int nt = 0; nt < 8; ++nt) bb[nt] = bi[w*128 + nt*16 + lr];
    #pragma unroll
    for (int r = 0; r < 4; ++r){
      size_t node = nb + lg*4 + r;
      u32x4 pu;
      pu.x = pk2(au[0][r]+bb[0], au[1][r]+bb[1]);
      pu.y = pk2(au[2][r]+bb[2], au[3][r]+bb[3]);
      pu.z = pk2(au[4][r]+bb[4], au[5][r]+bb[5]);
      pu.w = pk2(au[6][r]+bb[6], au[7][r]+bb[7]);
      *(u32x4*)(uu_t + node*512 + lr*32 + w*8) = pu;
      u32x4 pv;
      pv.x = pk2(av[0][r], av[1][r]); pv.y = pk2(av[2][r], av[3][r]);
      pv.z = pk2(av[4][r], av[5][r]); pv.w = pk2(av[6][r], av[7][r]);
      *(u32x4*)(v16_t + node*512 + lr*32 + w*8) = pv;
    }
  }

  // ================= part 2: tensor_init layer 1 =================
  f32x4 acc[3];
  #pragma unroll
  for (int ti = 0; ti < 3; ++ti) acc[ti] = (f32x4){0,0,0,0};
  #pragma unroll
  for (int ks = 0; ks < 4; ++ks){
    for (int ti = 0; ti < ntile; ++ti){
      const u16* b = W1s + (tiles[ti]*16 + lr)*128 + lg*8 + ks*32;
      short8 bH = *(const short8*)b;
      short8 bL = *(const short8*)(b + 18432);
      acc[ti] = __builtin_amdgcn_mfma_f32_16x16x32_bf16(aH[ks], bH, acc[ti], 0, 0, 0);
      acc[ti] = __builtin_amdgcn_mfma_f32_16x16x32_bf16(aL[ks], bH, acc[ti], 0, 0, 0);
      acc[ti] = __builtin_amdgcn_mfma_f32_16x16x32_bf16(aH[ks], bL, acc[ti], 0, 0, 0);
    }
  }
  for (int ti = 0; ti < ntile; ++ti){
    float bb = b1[tiles[ti]*16 + lr];
    #pragma unroll
    for (int r = 0; r < 4; ++r) acc[ti][r] += bb;
  }
  {
    float ps[4], pq[4];
    #pragma unroll
    for (int r = 0; r < 4; ++r){
      float s = 0.f, q = 0.f;
      for (int ti = 0; ti < ntile; ++ti){ s += acc[ti][r]; q += acc[ti][r]*acc[ti][r]; }
      ps[r] = s; pq[r] = q;
    }
    #pragma unroll
    for (int off = 1; off < 16; off <<= 1)
      #pragma unroll
      for (int r = 0; r < 4; ++r){ ps[r] += __shfl_xor(ps[r], off); pq[r] += __shfl_xor(pq[r], off); }
    if (lr == 0){
      #pragma unroll
      for (int r = 0; r < 4; ++r){
        pool[w*32 + (lg*4 + r)*2 + 0] = ps[r];
        pool[w*32 + (lg*4 + r)*2 + 1] = pq[r];
      }
    }
  }
  __syncthreads();
  if (t < 16){
    float s = pool[t*2] + pool[32 + t*2] + pool[64 + t*2] + pool[96 + t*2];
    float q = pool[t*2+1] + pool[32 + t*2+1] + pool[64 + t*2+1] + pool[96 + t*2+1];
    float mu = s * (1.0f/144.0f);
    pool[128 + t] = mu;
    pool[144 + t] = rsqrtf(q * (1.0f/144.0f) - mu*mu + 1e-5f);
  }
  __syncthreads();
  for (int ti = 0; ti < ntile; ++ti){
    int col = tiles[ti]*16 + lr;
    float gg = g1[col], bb = be1[col];
    #pragma unroll
    for (int r = 0; r < 4; ++r){
      int node = lg*4 + r;
      float mu = pool[128 + node], rs = pool[144 + node];
      t1s[node*164 + col] = siluf_((acc[ti][r] - mu) * rs * gg + bb);
    }
  }
  t1s[(t >> 4)*164 + 144 + (t & 15)] = 0.f;
  __syncthreads();

  // ================= layer 2 (K=160 padded) =================
  #pragma unroll
  for (int ti = 0; ti < 3; ++ti) acc[ti] = (f32x4){0,0,0,0};
  #pragma unroll
  for (int ks = 0; ks < 5; ++ks){
    float4 x0 = *(const float4*)&t1s[lr*164 + lg*8 + ks*32];
    float4 x1 = *(const float4*)&t1s[lr*164 + lg*8 + ks*32 + 4];
    float xs[8] = {x0.x, x0.y, x0.z, x0.w, x1.x, x1.y, x1.z, x1.w};
    short8 a2H, a2L;
    #pragma unroll
    for (int j = 0; j < 8; ++j){
      u16 hh = f2bf(xs[j]);
      a2H[j] = (short)hh;
      a2L[j] = (short)f2bf(xs[j] - bf2f(hh));
    }
    for (int ti = 0; ti < ntile; ++ti){
      const u16* b = W2s + (tiles[ti]*16 + lr)*160 + lg*8 + ks*32;
      short8 bH = *(const short8*)b;
      short8 bL = *(const short8*)(b + 23040);
      acc[ti] = __builtin_amdgcn_mfma_f32_16x16x32_bf16(a2H, bH, acc[ti], 0, 0, 0);
      acc[ti] = __builtin_amdgcn_mfma_f32_16x16x32_bf16(a2L, bH, acc[ti], 0, 0, 0);
      acc[ti] = __builtin_amdgcn_mfma_f32_16x16x32_bf16(a2H, bL, acc[ti], 0, 0, 0);
    }
  }
  for (int ti = 0; ti < ntile; ++ti){
    float bb = b2[tiles[ti]*16 + lr];
    #pragma unroll
    for (int r = 0; r < 4; ++r) acc[ti][r] += bb;
  }
  __syncthreads();
  {
    float ps[4], pq[4];
    #pragma unroll
    for (int r = 0; r < 4; ++r){
      float s = 0.f, q = 0.f;
      for (int ti = 0; ti < ntile; ++ti){ s += acc[ti][r]; q += acc[ti][r]*acc[ti][r]; }
      ps[r] = s; pq[r] = q;
    }
    #pragma unroll
    for (int off = 1; off < 16; off <<= 1)
      #pragma unroll
      for (int r = 0; r < 4; ++r){ ps[r] += __shfl_xor(ps[r], off); pq[r] += __shfl_xor(pq[r], off); }
    if (lr == 0){
      #pragma unroll
      for (int r = 0; r < 4; ++r){
        pool[w*32 + (lg*4 + r)*2 + 0] = ps[r];
        pool[w*32 + (lg*4 + r)*2 + 1] = pq[r];
      }
    }
  }
  __syncthreads();
  if (t < 16){
    float s = pool[t*2] + pool[32 + t*2] + pool[64 + t*2] + pool[96 + t*2];
    float q = pool[t*2+1] + pool[32 + t*2+1] + pool[64 + t*2+1] + pool[96 + t*2+1];
    float mu = s * (1.0f/144.0f);
    pool[128 + t] = mu;
    pool[144 + t] = rsqrtf(q * (1.0f/144.0f) - mu*mu + 1e-5f);
  }
  __syncthreads();
  for (int ti = 0; ti < ntile; ++ti){
    int col = tiles[ti]*16 + lr;
    float gg = g2[col], bb = be2[col];
    int c = col / 9, m = col - c*9;
    #pragma unroll
    for (int r = 0; r < 4; ++r){
      int node = lg*4 + r;
      float mu = pool[128 + node], rs = pool[144 + node];
      float val = siluf_((acc[ti][r] - mu) * rs * gg + bb);
      tens_t[(size_t)(nb + node)*144 + m*16 + c] = val;
    }
  }
}

// ---------------- edge_par: one thread per (edge, channel); single pass, bf16 tn ----------------
__global__ __launch_bounds__(256) void edge_par_k(
    const u16* __restrict__ uu_t, const u16* __restrict__ v16_t,
    const float* __restrict__ frames, const float* __restrict__ tens_t,
    const float* __restrict__ gt, const float* __restrict__ bet,
    const u16* __restrict__ srow, const u16* __restrict__ scol,
    uint32* __restrict__ tn)
{
  const int t = threadIdx.x;
  const int le = t >> 4, c = t & 15;
  const int e = blockIdx.x*16 + le;
  const int row = (int)srow[e], col = (int)scol[e];

  // ---- z[k] = u[col][c,k] + v[row][c,k] ----
  float z[32];
  {
    const u16* up = uu_t + (size_t)col*512 + c*32;
    const u16* vp = v16_t + (size_t)row*512 + c*32;
    #pragma unroll
    for (int q = 0; q < 4; ++q){
      u32x4 ua = *(const u32x4*)(up + q*8);
      u32x4 va = *(const u32x4*)(vp + q*8);
      z[q*8+0] = bflo(ua.x)+bflo(va.x); z[q*8+1] = bfhi(ua.x)+bfhi(va.x);
      z[q*8+2] = bflo(ua.y)+bflo(va.y); z[q*8+3] = bfhi(ua.y)+bfhi(va.y);
      z[q*8+4] = bflo(ua.z)+bflo(va.z); z[q*8+5] = bfhi(ua.z)+bfhi(va.z);
      z[q*8+6] = bflo(ua.w)+bflo(va.w); z[q*8+7] = bfhi(ua.w)+bfhi(va.w);
    }
  }

  // ---- LN over 512 ----
  float s = 0.f, q2 = 0.f;
  #pragma unroll
  for (int k = 0; k < 32; ++k){ s += z[k]; q2 += z[k]*z[k]; }
  #pragma unroll
  for (int off = 1; off < 16; off <<= 1){ s += __shfl_xor(s, off); q2 += __shfl_xor(q2, off); }
  float mu = s * (1.0f/512.0f);
  float rs = rsqrtf(q2 * (1.0f/512.0f) - mu*mu + 1e-5f);

  // ---- w = sigmoid(LN(z)) ----
  {
    const float* gp = gt  + c*32;
    const float* bp = bet + c*32;
    #pragma unroll
    for (int kq = 0; kq < 8; ++kq){
      float4 g4 = *(const float4*)(gp + kq*4);
      float4 b4 = *(const float4*)(bp + kq*4);
      z[kq*4+0] = sigmoidf_((z[kq*4+0]-mu)*rs*g4.x + b4.x);
      z[kq*4+1] = sigmoidf_((z[kq*4+1]-mu)*rs*g4.y + b4.y);
      z[kq*4+2] = sigmoidf_((z[kq*4+2]-mu)*rs*g4.z + b4.z);
      z[kq*4+3] = sigmoidf_((z[kq*4+3]-mu)*rs*g4.w + b4.w);
    }
  }

  // ---- ti-part (k<16) and G (k>=16) ----
  float o[9], G[9];
  {
    const float* ti = tens_t + (size_t)col*144;
    const float* tj = tens_t + (size_t)row*144;
    #pragma unroll
    for (int m = 0; m < 9; ++m){
      float a = 0.f, g = 0.f;
      #pragma unroll
      for (int kq = 0; kq < 4; ++kq){
        float4 t4 = *(const float4*)(ti + m*16 + kq*4);
        a += t4.x*z[kq*4+0] + t4.y*z[kq*4+1] + t4.z*z[kq*4+2] + t4.w*z[kq*4+3];
        float4 u4 = *(const float4*)(tj + m*16 + kq*4);
        g += u4.x*z[16+kq*4+0] + u4.y*z[16+kq*4+1] + u4.z*z[16+kq*4+2] + u4.w*z[16+kq*4+3];
      }
      o[m] = a; G[m] = g;
    }
  }

  // ---- R = Ri^T Rj ; o += R G R ----
  {
    const float* Ri = frames + (size_t)col*9;
    const float* Rj = frames + (size_t)row*9;
    float R[9];
    #pragma unroll
    for (int i = 0; i < 3; ++i)
      #pragma unroll
      for (int j = 0; j < 3; ++j)
        R[i*3+j] = Ri[i]*Rj[j] + Ri[3+i]*Rj[3+j] + Ri[6+i]*Rj[6+j];
    float A[9];
    #pragma unroll
    for (int i = 0; i < 3; ++i)
      #pragma unroll
      for (int j = 0; j < 3; ++j)
        A[i*3+j] = R[i*3+0]*G[0+j] + R[i*3+1]*G[3+j] + R[i*3+2]*G[6+j];
    #pragma unroll
    for (int i = 0; i < 3; ++i)
      #pragma unroll
      for (int j = 0; j < 3; ++j)
        o[i*3+j] += A[i*3+0]*R[0+j] + A[i*3+1]*R[3+j] + A[i*3+2]*R[6+j];
  }

  // ---- symmetrize -> 6 bf16 (3 dwords) ----
  float s01 = 0.5f*(o[1]+o[3]), s02 = 0.5f*(o[2]+o[6]), s12 = 0.5f*(o[5]+o[7]);
  uint32* tp = tn + (size_t)e*48 + c*3;
  tp[0] = pk2(o[0], s01);
  tp[1] = pk2(s02, o[4]);
  tp[2] = pk2(s12, o[8]);
}

// ---------------- segsum: thread per (node, channel); sequential CSR-range sum ----------------
__global__ __launch_bounds__(256) void segsum_k(
    const uint32* __restrict__ tn, const uint32* __restrict__ start,
    float* __restrict__ out)
{
  int tid = blockIdx.x*256 + threadIdx.x;
  if (tid >= NN*16) return;
  int n = tid >> 4, c = tid & 15;
  uint32 beg = (n == 0) ? 0u : start[n-1];
  uint32 end = start[n];

  float a0=0.f, a1=0.f, a2=0.f, a3=0.f, a4=0.f, a5=0.f;
  for (uint32 i = beg; i < end; ++i){
    const uint32* tp = tn + (size_t)i*48 + c*3;
    uint32 x0 = tp[0], x1 = tp[1], x2 = tp[2];
    a0 += bflo(x0); a1 += bfhi(x0);
    a2 += bflo(x1); a3 += bfhi(x1);
    a4 += bflo(x2); a5 += bfhi(x2);
  }

  float* op = out + (size_t)n*144 + c*9;
  op[0] = a0; op[1] = a1; op[2] = a2;
  op[3] = a1; op[4] = a3; op[5] = a4;
  op[6] = a2; op[7] = a4; op[8] = a5;
}

extern "C" void kernel_launch(void* const* d_in, const int* in_sizes, int n_in,
                              void* d_out, int out_size, void* d_ws, size_t ws_size,
                              hipStream_t stream) {
    const float* h      = (const float*)d_in[1];
    const float* frames = (const float*)d_in[2];
    const int*   ei     = (const int*)d_in[3];
    const float* W1  = (const float*)d_in[5];
    const float* b1  = (const float*)d_in[6];
    const float* g1  = (const float*)d_in[7];
    const float* be1 = (const float*)d_in[8];
    const float* W2  = (const float*)d_in[9];
    const float* b2  = (const float*)d_in[10];
    const float* g2  = (const float*)d_in[11];
    const float* be2 = (const float*)d_in[12];
    const float* Wi  = (const float*)d_in[13];
    const float* bi  = (const float*)d_in[14];
    const float* gi  = (const float*)d_in[15];
    const float* bei = (const float*)d_in[16];

    float* out = (float*)d_out;

    // ws layout (138.33 MB <= proven 140.68 MB):
    u16*    uu_t  = (u16*)d_ws;                             // [N,512] bf16: 30,720,000
    u16*    v16_t = (u16*)  ((char*)d_ws + 30720000);       // [N,512] bf16: 30,720,000
    float*  tens_t= (float*)((char*)d_ws + 61440000);       // [N,144] f32 : 17,280,000
    u16*    Wq    = (u16*)  ((char*)d_ws + 78720000);       // 524,288
    u16*    W1s   = (u16*)  ((char*)d_ws + 79244288);       // 73,728
    u16*    W2s   = (u16*)  ((char*)d_ws + 79318016);       // 92,160
    float*  gt    = (float*)((char*)d_ws + 79410176);       // 2,048
    float*  bet   = (float*)((char*)d_ws + 79412224);       // 2,048
    uint32* start = (uint32*)((char*)d_ws + 79414272);      // 120,000
    u16*    srow  = (u16*)  ((char*)d_ws + 79534272);       // 600,000
    u16*    scol  = (u16*)  ((char*)d_ws + 80134272);       // 600,000
    uint32* tn    = (uint32*)((char*)d_ws + 80734272);      // [E,16,3] u32 (bf16x2): 57,600,000

    hipMemsetAsync(start, 0, NN * sizeof(uint32), stream);

    cvt_all_k<<<256, 256, 0, stream>>>(Wi, Wq, W1, W1s, W2, W2s, gi, bei, gt, bet);
    node_all_k<<<NN/16, 256, 0, stream>>>(h, Wq, bi, W1s, W2s, b1, g1, be1, b2, g2, be2,
                                          uu_t, v16_t, tens_t);
    hist_k<<<(EE + 255)/256, 256, 0, stream>>>(ei, start);
    scan_k<<<1, 1024, 0, stream>>>(start);
    scatter_k<<<(EE + 255)/256, 256, 0, stream>>>(ei, start, srow, scol);
    edge_par_k<<<EE/16, 256, 0, stream>>>(uu_t, v16_t, frames, tens_t, gt, bet, srow, scol, tn);
    segsum_k<<<(NN*16 + 255)/256, 256, 0, stream>>>(tn, start, out);
}